// Round 5
// baseline (323.267 us; speedup 1.0000x reference)
//
#include <hip/hip_runtime.h>

#define NDFF 2048
#define NVOC 10000
#define SIGMA 0.1f

typedef float f32x4 __attribute__((ext_vector_type(4)));

// ---- output offsets (floats) ----
#define O0 0
#define O1 65536
#define O2 131072
#define O3 211072
#define O4 291072
#define O5 371072
#define O6 436608
#define O7 502144
#define O8 34056576
#define O9 67611008
#define O10 67611136

// ---- workspace offsets (floats) ----
#define WQ    0
#define WK    65536
#define WV    131072
#define WZ    196608
#define WO1   262144
#define WH1   327680
#define WR    589824
#define WPRED 655360
#define WMAX  1935360
#define WSUM  1935488
#define WWSQ  1935616
#define WIT   1935744
#define WF2P  1936000   // 4 x 128 x 512
#define WSC   2198144   // 128 x 8 x 512 raw scores
#define WZP   2722432   // 8 x 128 x 512 pv partials

// ===== fused QKV projection: out = r @ W + b + SIGMA*eps =====
// grid (4 coltiles of 128, 8 rowgroups of 16, 3 matrices), 512 thr
__global__ __launch_bounds__(512)
void k_qkv(const float* __restrict__ r,
           const float* __restrict__ Wq, const float* __restrict__ bq, const float* __restrict__ eq, float* __restrict__ oq,
           const float* __restrict__ Wk, const float* __restrict__ bk, const float* __restrict__ ek, float* __restrict__ ok,
           const float* __restrict__ Wv, const float* __restrict__ bv, const float* __restrict__ ev, float* __restrict__ ov)
{
    const float *W, *bias, *eps; float* out;
    if (blockIdx.z == 0)      { W = Wq; bias = bq; eps = eq; out = oq; }
    else if (blockIdx.z == 1) { W = Wk; bias = bk; eps = ek; out = ok; }
    else                      { W = Wv; bias = bv; eps = ev; out = ov; }
    int tid = threadIdx.x;
    int col = tid & 127, kq = tid >> 7;
    int colg = blockIdx.x * 128 + col;
    int row0 = blockIdx.y * 16;
    __shared__ float rs[16][512];
#pragma unroll
    for (int j = 0; j < 16; j++) {
        int idx = tid + j * 512;
        rs[idx >> 9][idx & 511] = r[(row0 + (idx >> 9)) * 512 + (idx & 511)];
    }
    __syncthreads();
    float acc[16];
#pragma unroll
    for (int p = 0; p < 16; p++) acc[p] = 0.f;
    const float* Wp = W + (kq * 128) * 512 + colg;
#pragma unroll 8
    for (int d = 0; d < 128; d++) {
        float wv = Wp[d * 512];
#pragma unroll
        for (int p = 0; p < 16; p++) acc[p] += rs[p][kq * 128 + d] * wv;
    }
    __syncthreads();
    float (*part)[16][128] = (float(*)[16][128])rs;
#pragma unroll
    for (int p = 0; p < 16; p++) part[kq][p][col] = acc[p];
    __syncthreads();
#pragma unroll
    for (int j = 0; j < 4; j++) {
        int idx = tid + j * 512;
        int p = idx >> 7, c = idx & 127;
        int cg = blockIdx.x * 128 + c;
        float v = part[0][p][c] + part[1][p][c] + part[2][p][c] + part[3][p][c]
                + bias[cg] + SIGMA * eps[(row0 + p) * 512 + cg];
        out[(row0 + p) * 512 + cg] = v;
    }
}

// ===== attention scores (raw): grid (128 bp, 8 schunk), 512 thr =====
__global__ __launch_bounds__(512)
void k_score(const float* __restrict__ qws, const float* __restrict__ kws,
             const float* __restrict__ Kin, const int* __restrict__ t_ptr,
             float* __restrict__ scw)
{
    int t = *t_ptr;
    int bp = blockIdx.x;
    int len = (t + 8) >> 3;
    int lo = blockIdx.y * len;
    int hi = min(lo + len, t + 1);
    int tid = threadIdx.x;
    int wave = tid >> 6, lane = tid & 63;
    const float4* q4 = (const float4*)(qws + bp * 512);
    float4 qa = q4[lane * 2], qb = q4[lane * 2 + 1];
    for (int s = lo + wave; s < hi; s += 8) {
        const float4* kr = (s == t) ? (const float4*)(kws + bp * 512)
                                    : (const float4*)(Kin + (bp * 512 + s) * 512);
        float4 a = kr[lane * 2], c = kr[lane * 2 + 1];
        float partial = qa.x * a.x + qa.y * a.y + qa.z * a.z + qa.w * a.w
                      + qb.x * c.x + qb.y * c.y + qb.z * c.z + qb.w * c.w;
#pragma unroll
        for (int m = 1; m < 8; m <<= 1) partial += __shfl_xor(partial, m, 64);
        if ((lane & 7) == 0) scw[(bp * 8 + (lane >> 3)) * 512 + s] = partial * 0.125f;
    }
}

// ===== PV with fused softmax: grid (128 bp, 8 schunk), 512 thr =====
__global__ __launch_bounds__(512)
void k_pv(const float* __restrict__ scw, const float* __restrict__ vws,
          const float* __restrict__ Vin, const int* __restrict__ t_ptr,
          float* __restrict__ zpart, float* __restrict__ out)
{
    int t = *t_ptr;
    int bp = blockIdx.x;
    int sc = blockIdx.y;
    int len = (t + 8) >> 3;
    int lo = sc * len;
    int hi = min(lo + len, t + 1);
    int tid = threadIdx.x;
    int wave = tid >> 6, lane = tid & 63;
    __shared__ float smh[8], ssh[8];
    __shared__ float sa[8][68];
    {
        const float* sp = scw + (bp * 8 + wave) * 512;
        float m = -3.0e38f;
        for (int s = lane; s <= t; s += 64) m = fmaxf(m, sp[s]);
#pragma unroll
        for (int o = 32; o; o >>= 1) m = fmaxf(m, __shfl_xor(m, o, 64));
        float sum = 0.f;
        for (int s = lane; s <= t; s += 64) sum += __expf(sp[s] - m);
#pragma unroll
        for (int o = 32; o; o >>= 1) sum += __shfl_xor(sum, o, 64);
        if (lane == 0) { smh[wave] = m; ssh[wave] = 1.f / sum; }
    }
    __syncthreads();
    for (int idx = tid; idx < 8 * len; idx += 512) {
        int hh = idx / len, j = idx - hh * len;
        int s = lo + j;
        sa[hh][j] = (s < hi) ? __expf(scw[(bp * 8 + hh) * 512 + s] - smh[hh]) * ssh[hh] : 0.f;
    }
    __syncthreads();
    int h = tid >> 6;
    float acc = 0.f;
    int hv = min(hi, t);
    int s = lo;
    for (; s + 4 <= hv; s += 4) {
        float v0 = __builtin_nontemporal_load(&Vin[(bp * 512 + s + 0) * 512 + tid]);
        float v1 = __builtin_nontemporal_load(&Vin[(bp * 512 + s + 1) * 512 + tid]);
        float v2 = __builtin_nontemporal_load(&Vin[(bp * 512 + s + 2) * 512 + tid]);
        float v3 = __builtin_nontemporal_load(&Vin[(bp * 512 + s + 3) * 512 + tid]);
        acc += sa[h][s - lo] * v0 + sa[h][s + 1 - lo] * v1
             + sa[h][s + 2 - lo] * v2 + sa[h][s + 3 - lo] * v3;
    }
    for (; s < hv; s++) acc += sa[h][s - lo] * __builtin_nontemporal_load(&Vin[(bp * 512 + s) * 512 + tid]);
    if (t >= lo && t < hi) acc += sa[h][t - lo] * vws[bp * 512 + tid];
    zpart[sc * 65536 + bp * 512 + tid] = acc;
    if (sc == 0) {
        int ss = tid;
        float a = 0.f;
        if (ss <= t) {
#pragma unroll
            for (int hh = 0; hh < 8; hh++)
                a += __expf(scw[(bp * 8 + hh) * 512 + ss] - smh[hh]) * ssh[hh];
            a *= 0.125f;
        }
        out[O6 + bp * 512 + ss] = a;
    }
}

// ===== z projection: zh = sum8(zpart), zp = zh @ Wo + bo + SIGMA*eps_z =====
// grid (4 coltiles, 8 rowgroups of 16), 512 thr
__global__ __launch_bounds__(512)
void k_zproj(const float* __restrict__ zpart, const float* __restrict__ Wo,
             const float* __restrict__ bo, const float* __restrict__ epsz,
             float* __restrict__ out)
{
    int tid = threadIdx.x;
    int col = tid & 127, kq = tid >> 7;
    int colg = blockIdx.x * 128 + col;
    int row0 = blockIdx.y * 16;
    __shared__ float rs[16][512];
#pragma unroll
    for (int j = 0; j < 16; j++) {
        int idx2 = tid + j * 512;
        int rr = idx2 >> 9, cc = idx2 & 511;
        int gi = (row0 + rr) * 512 + cc;
        float v = 0.f;
#pragma unroll
        for (int jj = 0; jj < 8; jj++) v += zpart[jj * 65536 + gi];
        rs[rr][cc] = v;
    }
    __syncthreads();
    float acc[16];
#pragma unroll
    for (int p = 0; p < 16; p++) acc[p] = 0.f;
    const float* Wp = Wo + (kq * 128) * 512 + colg;
#pragma unroll 8
    for (int d = 0; d < 128; d++) {
        float wv = Wp[d * 512];
#pragma unroll
        for (int p = 0; p < 16; p++) acc[p] += rs[p][kq * 128 + d] * wv;
    }
    __syncthreads();
    float (*part)[16][128] = (float(*)[16][128])rs;
#pragma unroll
    for (int p = 0; p < 16; p++) part[kq][p][col] = acc[p];
    __syncthreads();
#pragma unroll
    for (int j = 0; j < 4; j++) {
        int idx = tid + j * 512;
        int p = idx >> 7, c = idx & 127;
        int cg = blockIdx.x * 128 + c;
        out[(row0 + p) * 512 + cg] = part[0][p][c] + part[1][p][c] + part[2][p][c] + part[3][p][c]
                                   + bo[cg] + SIGMA * epsz[(row0 + p) * 512 + cg];
    }
}

// ===== ffn1 with fused LN1: h1 = relu(LN(zp+r) @ W1 + b1); coltile0 writes o1 =====
// grid (16 coltiles, 8 rowgroups of 16), 512 thr
__global__ __launch_bounds__(512)
void k_ffn1(const float* __restrict__ zp, const float* __restrict__ r,
            const float* __restrict__ g, const float* __restrict__ be,
            const float* __restrict__ W1, const float* __restrict__ b1,
            float* __restrict__ o1, float* __restrict__ h1)
{
    int tid = threadIdx.x;
    int col = tid & 127, kq = tid >> 7;
    int colg = blockIdx.x * 128 + col;
    int row0 = blockIdx.y * 16;
    __shared__ float rs[16][512];
    __shared__ float sm[16], si[16];
#pragma unroll
    for (int j = 0; j < 16; j++) {
        int idx = tid + j * 512;
        int rr = idx >> 9, cc = idx & 511;
        int gi = (row0 + rr) * 512 + cc;
        rs[rr][cc] = zp[gi] + r[gi];
    }
    __syncthreads();
    {
        int wave = tid >> 6, lane = tid & 63;
        int row = wave * 2 + (lane >> 5);
        int l = lane & 31;
        float s = 0.f;
        for (int c = l; c < 512; c += 32) s += rs[row][c];
#pragma unroll
        for (int o = 16; o; o >>= 1) s += __shfl_xor(s, o, 64);
        float mu = s * (1.f / 512.f);
        float v = 0.f;
        for (int c = l; c < 512; c += 32) { float dx = rs[row][c] - mu; v += dx * dx; }
#pragma unroll
        for (int o = 16; o; o >>= 1) v += __shfl_xor(v, o, 64);
        if (l == 0) { sm[row] = mu; si[row] = rsqrtf(v * (1.f / 512.f) + 1e-6f); }
    }
    __syncthreads();
#pragma unroll
    for (int j = 0; j < 16; j++) {
        int idx = tid + j * 512;
        int rr = idx >> 9, cc = idx & 511;
        float val = (rs[rr][cc] - sm[rr]) * si[rr] * g[cc] + be[cc];
        rs[rr][cc] = val;
        if (blockIdx.x == 0) o1[(row0 + rr) * 512 + cc] = val;
    }
    __syncthreads();
    float acc[16];
#pragma unroll
    for (int p = 0; p < 16; p++) acc[p] = 0.f;
    const float* Wp = W1 + (kq * 128) * NDFF + colg;
#pragma unroll 8
    for (int d = 0; d < 128; d++) {
        float wv = Wp[d * NDFF];
#pragma unroll
        for (int p = 0; p < 16; p++) acc[p] += rs[p][kq * 128 + d] * wv;
    }
    __syncthreads();
    float (*part)[16][128] = (float(*)[16][128])rs;
#pragma unroll
    for (int p = 0; p < 16; p++) part[kq][p][col] = acc[p];
    __syncthreads();
#pragma unroll
    for (int j = 0; j < 4; j++) {
        int idx = tid + j * 512;
        int p = idx >> 7, c = idx & 127;
        int cg = blockIdx.x * 128 + c;
        float v = part[0][p][c] + part[1][p][c] + part[2][p][c] + part[3][p][c] + b1[cg];
        h1[(row0 + p) * NDFF + cg] = fmaxf(v, 0.f);
    }
}

// ===== ffn2 partials: grid (4 coltiles, 8 rowgroups of 16, 4 ksect of 512), 512 thr =====
__global__ __launch_bounds__(512)
void k_ffn2p(const float* __restrict__ h1, const float* __restrict__ W2,
             float* __restrict__ f2p)
{
    int tid = threadIdx.x;
    int col = tid & 127, kq = tid >> 7;
    int colg = blockIdx.x * 128 + col;
    int row0 = blockIdx.y * 16;
    int ks = blockIdx.z;
    __shared__ float rs[16][512];
#pragma unroll
    for (int j = 0; j < 16; j++) {
        int idx = tid + j * 512;
        rs[idx >> 9][idx & 511] = h1[(row0 + (idx >> 9)) * NDFF + ks * 512 + (idx & 511)];
    }
    __syncthreads();
    float acc[16];
#pragma unroll
    for (int p = 0; p < 16; p++) acc[p] = 0.f;
    const float* Wp = W2 + (ks * 512 + kq * 128) * 512 + colg;
#pragma unroll 8
    for (int d = 0; d < 128; d++) {
        float wv = Wp[d * 512];
#pragma unroll
        for (int p = 0; p < 16; p++) acc[p] += rs[p][kq * 128 + d] * wv;
    }
    __syncthreads();
    float (*part)[16][128] = (float(*)[16][128])rs;
#pragma unroll
    for (int p = 0; p < 16; p++) part[kq][p][col] = acc[p];
    __syncthreads();
#pragma unroll
    for (int j = 0; j < 4; j++) {
        int idx = tid + j * 512;
        int p = idx >> 7, c = idx & 127;
        int cg = blockIdx.x * 128 + c;
        f2p[ks * 65536 + (row0 + p) * 512 + cg] =
            part[0][p][c] + part[1][p][c] + part[2][p][c] + part[3][p][c];
    }
}

// ===== pred with fused LN3: pred = LN(sum(f2p)+b2+o1) @ Wout + bout =====
// grid (40 coltiles of 256, 4 rowgroups of 32), 512 thr
__global__ __launch_bounds__(512)
void k_pred(const float* __restrict__ f2p, const float* __restrict__ b2,
            const float* __restrict__ o1, const float* __restrict__ g3,
            const float* __restrict__ b3, const float* __restrict__ Wout,
            const float* __restrict__ bout, float* __restrict__ pred)
{
    int tid = threadIdx.x;
    int col = tid & 255, kh = tid >> 8;
    int colg = blockIdx.x * 256 + col;
    int colL = min(colg, NVOC - 1);
    int row0 = blockIdx.y * 32;
    __shared__ float rs[32][512];
    __shared__ float sm[32], si[32];
#pragma unroll
    for (int j = 0; j < 32; j++) {
        int idx = tid + j * 512;
        int rr = idx >> 9, cc = idx & 511;
        int gi = (row0 + rr) * 512 + cc;
        rs[rr][cc] = f2p[gi] + f2p[65536 + gi] + f2p[131072 + gi] + f2p[196608 + gi]
                   + b2[cc] + o1[gi];
    }
    __syncthreads();
    {
        int wave = tid >> 6, lane = tid & 63;
        int row = wave * 4 + (lane >> 4);
        int l = lane & 15;
        float s = 0.f;
        for (int c = l; c < 512; c += 16) s += rs[row][c];
#pragma unroll
        for (int o = 8; o; o >>= 1) s += __shfl_xor(s, o, 64);
        float mu = s * (1.f / 512.f);
        float v = 0.f;
        for (int c = l; c < 512; c += 16) { float dx = rs[row][c] - mu; v += dx * dx; }
#pragma unroll
        for (int o = 8; o; o >>= 1) v += __shfl_xor(v, o, 64);
        if (l == 0) { sm[row] = mu; si[row] = rsqrtf(v * (1.f / 512.f) + 1e-6f); }
    }
    __syncthreads();
#pragma unroll
    for (int j = 0; j < 32; j++) {
        int idx = tid + j * 512;
        int rr = idx >> 9, cc = idx & 511;
        rs[rr][cc] = (rs[rr][cc] - sm[rr]) * si[rr] * g3[cc] + b3[cc];
    }
    __syncthreads();
    float acc[32];
#pragma unroll
    for (int p = 0; p < 32; p++) acc[p] = 0.f;
#pragma unroll
    for (int kc = 0; kc < 2; kc++) {
        const float* Wp = Wout + (kc * 256 + kh * 128) * NVOC + colL;
#pragma unroll 4
        for (int d = 0; d < 128; d++) {
            float wv = Wp[d * NVOC];
#pragma unroll
            for (int p = 0; p < 32; p++) acc[p] += rs[p][kc * 256 + kh * 128 + d] * wv;
        }
    }
    __syncthreads();
    float (*part)[256] = (float(*)[256])rs;
    if (kh == 1) {
#pragma unroll
        for (int p = 0; p < 32; p++) part[p][col] = acc[p];
    }
    __syncthreads();
    if (kh == 0 && colg < NVOC) {
        float bv = bout[colg];
#pragma unroll
        for (int p = 0; p < 32; p++)
            pred[(row0 + p) * NVOC + colg] = acc[p] + part[p][col] + bv;
    }
}

// ===== per-row softmax stats + w_sq. grid 128, 512 thr =====
__global__ __launch_bounds__(512)
void k_soft(const float* __restrict__ pred, const int* __restrict__ x,
            float* __restrict__ rowmax, float* __restrict__ rowsum,
            float* __restrict__ wsq, float* __restrict__ out)
{
    __shared__ float red[8];
    int row = blockIdx.x, tid = threadIdx.x;
    const float* pr = pred + row * NVOC;
    float m = -3.0e38f;
    for (int v = tid; v < NVOC; v += 512) m = fmaxf(m, pr[v]);
#pragma unroll
    for (int o = 32; o; o >>= 1) m = fmaxf(m, __shfl_xor(m, o, 64));
    if ((tid & 63) == 0) red[tid >> 6] = m;
    __syncthreads();
#pragma unroll
    for (int i = 0; i < 8; i++) m = fmaxf(m, red[i]);
    __syncthreads();
    float s = 0.f;
    for (int v = tid; v < NVOC; v += 512) s += __expf(pr[v] - m);
#pragma unroll
    for (int o = 32; o; o >>= 1) s += __shfl_xor(s, o, 64);
    if ((tid & 63) == 0) red[tid >> 6] = s;
    __syncthreads();
    if (tid == 0) {
        float tot = 0.f;
#pragma unroll
        for (int i = 0; i < 8; i++) tot += red[i];
        rowmax[row] = m; rowsum[row] = tot;
        int b = row >> 4;
        float w = __expf(pr[x[b]] - m) / tot;
        wsq[row] = w;
        out[O9 + row] = w;
    }
}

// ===== vocab outputs + it/amw computation. grid (20, 8), 512 thr =====
__global__ __launch_bounds__(512)
void k_vocab(const float* __restrict__ pred, const float* __restrict__ rowmax,
             const float* __restrict__ rowsum, const float* __restrict__ wsq,
             const float* __restrict__ gumbel, int* __restrict__ it,
             float* __restrict__ out)
{
    int b = blockIdx.y;
    int tid = threadIdx.x;
    __shared__ int s_amw;
    if (tid == 0) {
        float bw = -3.0e38f; int bj = 0;
#pragma unroll
        for (int pp = 0; pp < 16; pp++) {
            float wv = wsq[b * 16 + pp];
            if (wv > bw) { bw = wv; bj = pp; }
        }
        s_amw = bj;
    }
    if (blockIdx.x == 0 && tid < 16) {
        float best = -3.0e38f; int bi = 0;
#pragma unroll
        for (int pp = 0; pp < 16; pp++) {
            float v = logf(wsq[b * 16 + pp] + 1e-10f) + gumbel[(b * 16 + tid) * 16 + pp];
            if (v > best) { best = v; bi = pp; }
        }
        it[b * 16 + tid] = bi;
    }
    __syncthreads();
    int v = blockIdx.x * 512 + tid;
    if (v >= NVOC) return;
    int amw = s_amw;
    float ga = 0.f, as = 0.f;
#pragma unroll
    for (int p = 0; p < 16; p++) {
        int rr = b * 16 + p;
        float pv = pred[rr * NVOC + v];
        ga += pv;
        as += __expf(pv - rowmax[rr]) * (1.f / rowsum[rr]);
    }
    out[O3 + b * NVOC + v] = ga * (1.f / 16.f);
    out[O2 + b * NVOC + v] = as * (1.f / 16.f);
    out[O4 + b * NVOC + v] = pred[(b * 16 + amw) * NVOC + v];
}

// ===== K / Vs resample + misc outputs. grid 4096 x 256 grid-stride =====
__global__ __launch_bounds__(256)
void k_resample(const float* __restrict__ Kin, const float* __restrict__ kws,
                const int* __restrict__ it, const int* __restrict__ t_ptr,
                const float* __restrict__ r, const float* __restrict__ epsz,
                const float* __restrict__ zws, const int* __restrict__ Iin,
                float* __restrict__ out)
{
    int t = *t_ptr;
    const f32x4* K4  = (const f32x4*)Kin;
    const f32x4* kw4 = (const f32x4*)kws;
    const f32x4* r4  = (const f32x4*)r;
    const f32x4* e4  = (const f32x4*)epsz;
    const f32x4* z4  = (const f32x4*)zws;
    f32x4* oK = (f32x4*)(out + O7);
    f32x4* oV = (f32x4*)(out + O8);
    const int total = 128 * 512 * 128;      // float4 units of K/Vs
    const int total2 = total + 16384;       // + misc (65536 floats)
    for (int i = blockIdx.x * 256 + threadIdx.x; i < total2; i += gridDim.x * 256) {
        if (i < total) {
            int lane = i & 127;
            int row = i >> 7;
            int s = row & 511;
            int bp = row >> 9;
            int b = bp >> 4;
            f32x4 vK, vV;
            if (s > t) {
                vK = __builtin_nontemporal_load(&K4[i]);
                vV = vK;
            } else {
                int ip = it[bp];
                int ip2 = it[b * 16 + ip];
                if (s == t) {
                    vK = kw4[(b * 16 + ip) * 128 + lane];
                    vV = kw4[(b * 16 + ip2) * 128 + lane];
                } else {
                    vK = K4[((b * 16 + ip) * 512 + s) * 128 + lane];
                    vV = K4[((b * 16 + ip2) * 512 + s) * 128 + lane];
                }
            }
            __builtin_nontemporal_store(vK, &oK[i]);
            __builtin_nontemporal_store(vV, &oV[i]);
        } else {
            int j = i - total;              // 0..16383 float4
            int fidx = j * 4;
            ((f32x4*)(out + O0))[j] = r4[j];
            ((f32x4*)(out + O5))[j] = e4[j];
            int row = fidx >> 9, d0 = fidx & 511;
            int b = row >> 4;
            int ip = it[row];
            ((f32x4*)(out + O1))[j] = z4[((b * 16 + ip) << 7) + (d0 >> 2)];
#pragma unroll
            for (int k = 0; k < 4; k++) {
                int s = d0 + k;
                float iv;
                if (s < t)       iv = (float)Iin[((b * 16 + ip) << 9) + s];
                else if (s == t) iv = (float)ip;
                else             iv = (float)Iin[row * 512 + s];
                out[O10 + fidx + k] = iv;
            }
        }
    }
}

extern "C" void kernel_launch(void* const* d_in, const int* in_sizes, int n_in,
                              void* d_out, int out_size, void* d_ws, size_t ws_size,
                              hipStream_t stream) {
    const float* r      = (const float*)d_in[0];
    const int*   x      = (const int*)d_in[1];
    const float* Kin    = (const float*)d_in[2];
    const float* Vin    = (const float*)d_in[3];
    const int*   Iin    = (const int*)d_in[5];
    const int*   t_ptr  = (const int*)d_in[6];
    const float* eps_q  = (const float*)d_in[7];
    const float* eps_k  = (const float*)d_in[8];
    const float* eps_v  = (const float*)d_in[9];
    const float* eps_z  = (const float*)d_in[10];
    const float* gumbel = (const float*)d_in[11];
    const float* Wq = (const float*)d_in[12]; const float* bq = (const float*)d_in[13];
    const float* Wk = (const float*)d_in[14]; const float* bk = (const float*)d_in[15];
    const float* Wv = (const float*)d_in[16]; const float* bv = (const float*)d_in[17];
    const float* Wo = (const float*)d_in[18]; const float* bo = (const float*)d_in[19];
    const float* ln1_g = (const float*)d_in[20]; const float* ln1_b = (const float*)d_in[21];
    const float* ln3_g = (const float*)d_in[22]; const float* ln3_b = (const float*)d_in[23];
    const float* W1 = (const float*)d_in[24]; const float* b1 = (const float*)d_in[25];
    const float* W2 = (const float*)d_in[26]; const float* b2 = (const float*)d_in[27];
    const float* Wout = (const float*)d_in[28]; const float* bout = (const float*)d_in[29];

    float* ws  = (float*)d_ws;
    float* q   = ws + WQ;
    float* kv  = ws + WK;
    float* vv  = ws + WV;
    float* zp  = ws + WZ;
    float* o1  = ws + WO1;
    float* h1  = ws + WH1;
    float* pr  = ws + WPRED;
    float* rmx = ws + WMAX;
    float* rsm = ws + WSUM;
    float* wsq = ws + WWSQ;
    int*   itw = (int*)(ws + WIT);
    float* f2p = ws + WF2P;
    float* scw = ws + WSC;
    float* zpt = ws + WZP;
    float* outp = (float*)d_out;

    k_qkv<<<dim3(4, 8, 3), 512, 0, stream>>>(r, Wq, bq, eps_q, q, Wk, bk, eps_k, kv, Wv, bv, eps_v, vv);
    k_score<<<dim3(128, 8), 512, 0, stream>>>(q, kv, Kin, t_ptr, scw);
    k_pv<<<dim3(128, 8), 512, 0, stream>>>(scw, vv, Vin, t_ptr, zpt, outp);
    k_zproj<<<dim3(4, 8), 512, 0, stream>>>(zpt, Wo, bo, eps_z, zp);
    k_ffn1<<<dim3(16, 8), 512, 0, stream>>>(zp, r, ln1_g, ln1_b, W1, b1, o1, h1);
    k_ffn2p<<<dim3(4, 8, 4), 512, 0, stream>>>(h1, W2, f2p);
    k_pred<<<dim3(40, 4), 512, 0, stream>>>(f2p, b2, o1, ln3_g, ln3_b, Wout, bout, pr);
    k_soft<<<128, 512, 0, stream>>>(pr, x, rmx, rsm, wsq, outp);
    k_vocab<<<dim3(20, 8), 512, 0, stream>>>(pr, rmx, rsm, wsq, gumbel, itw, outp);
    k_resample<<<4096, 256, 0, stream>>>(Kin, kv, itw, t_ptr, r, eps_z, zp, Iin, outp);
}

// Round 6
// 265.617 us; speedup vs baseline: 1.2170x; 1.2170x over previous
//
#include <hip/hip_runtime.h>

#define NDFF 2048
#define NVOC 10000
#define SIGMA 0.1f

typedef float f32x4 __attribute__((ext_vector_type(4)));

// ---- output offsets (floats) ----
#define O0 0
#define O1 65536
#define O2 131072
#define O3 211072
#define O4 291072
#define O5 371072
#define O6 436608
#define O7 502144
#define O8 34056576
#define O9 67611008
#define O10 67611136

// ---- workspace offsets (floats) ----
#define WQ    0
#define WK    65536
#define WV    131072
#define WZH   196608
#define WZ    262144
#define WO1   327680
#define WH1   393216    // 262144
#define WR    655360
#define WPRED 720896    // 1280000
#define WMAX  2000896
#define WSUM  2001024
#define WWSQ  2001152
#define WIT   2001280
#define WF2P  2001536   // 262144
#define WSC   2263680   // 128 x 8 x 512 normalized attn

// ===== fused QKV projection: out = r @ W + b + SIGMA*eps =====
// grid (4 coltiles of 128, 16 rowgroups of 8, 3 matrices), 512 thr
__global__ __launch_bounds__(512)
void k_qkv(const float* __restrict__ r,
           const float* __restrict__ Wq, const float* __restrict__ bq, const float* __restrict__ eq, float* __restrict__ oq,
           const float* __restrict__ Wk, const float* __restrict__ bk, const float* __restrict__ ek, float* __restrict__ ok,
           const float* __restrict__ Wv, const float* __restrict__ bv, const float* __restrict__ ev, float* __restrict__ ov)
{
    const float *W, *bias, *eps; float* out;
    if (blockIdx.z == 0)      { W = Wq; bias = bq; eps = eq; out = oq; }
    else if (blockIdx.z == 1) { W = Wk; bias = bk; eps = ek; out = ok; }
    else                      { W = Wv; bias = bv; eps = ev; out = ov; }
    int tid = threadIdx.x;
    int col = tid & 127, kq = tid >> 7;
    int colg = blockIdx.x * 128 + col;
    int row0 = blockIdx.y * 8;
    __shared__ float rs[8][512];
#pragma unroll
    for (int p = 0; p < 8; p++) rs[p][tid & 511] = r[(row0 + p) * 512 + tid];
    __syncthreads();
    float acc[8] = {0,0,0,0,0,0,0,0};
    const float* Wp = W + (kq * 128) * 512 + colg;
#pragma unroll 8
    for (int d = 0; d < 128; d++) {
        float wv = Wp[d * 512];
#pragma unroll
        for (int p = 0; p < 8; p++) acc[p] += rs[p][kq * 128 + d] * wv;
    }
    __syncthreads();
    float (*part)[8][128] = (float(*)[8][128])rs;
#pragma unroll
    for (int p = 0; p < 8; p++) part[kq][p][col] = acc[p];
    __syncthreads();
#pragma unroll
    for (int j = 0; j < 2; j++) {
        int idx = tid + j * 512;
        int p = idx >> 7, c = idx & 127;
        int cg = blockIdx.x * 128 + c;
        float v = part[0][p][c] + part[1][p][c] + part[2][p][c] + part[3][p][c]
                + bias[cg] + SIGMA * eps[(row0 + p) * 512 + cg];
        out[(row0 + p) * 512 + cg] = v;
    }
}

// ===== fused attention: scores + softmax + PV per (bp, head) =====
// grid (128, 8), 256 thr. LDS: sc[512] + part[4][64].
__global__ __launch_bounds__(256)
void k_attn(const float* __restrict__ qws, const float* __restrict__ kws,
            const float* __restrict__ vws, const float* __restrict__ Kin,
            const float* __restrict__ Vin, const int* __restrict__ t_ptr,
            float* __restrict__ zh, float* __restrict__ scw)
{
    int t = *t_ptr;
    int bp = blockIdx.x, h = blockIdx.y;
    int tid = threadIdx.x;
    int wave = tid >> 6, lane = tid & 63;
    __shared__ float sc[512];
    __shared__ float red[4], red2[4];
    __shared__ float part[4][64];

    float4 qv = ((const float4*)(qws + bp * 512 + h * 64))[lane & 15];

    // Phase 1: scores. 16-lane groups each own one s; 4 s per wave-iter.
    for (int sb = wave * 4; sb <= t; sb += 16) {
        int s = sb + (lane >> 4);
        bool valid = (s <= t);
        int ss = valid ? s : t;
        const float4* kr = (ss == t) ? (const float4*)(kws + bp * 512 + h * 64)
                                     : (const float4*)(Kin + (bp * 512 + ss) * 512 + h * 64);
        float4 kv = kr[lane & 15];
        float p = qv.x * kv.x + qv.y * kv.y + qv.z * kv.z + qv.w * kv.w;
#pragma unroll
        for (int m = 1; m < 16; m <<= 1) p += __shfl_xor(p, m, 64);
        if ((lane & 15) == 0 && valid) sc[s] = p * 0.125f;
    }
    __syncthreads();

    // Phase 2: softmax over sc[0..t], cooperative across 4 waves.
    float lm = -3.0e38f;
    for (int s = tid; s <= t; s += 256) lm = fmaxf(lm, sc[s]);
#pragma unroll
    for (int o = 32; o; o >>= 1) lm = fmaxf(lm, __shfl_xor(lm, o, 64));
    if (lane == 0) red[wave] = lm;
    __syncthreads();
    float m = fmaxf(fmaxf(red[0], red[1]), fmaxf(red[2], red[3]));
    float ls = 0.f;
    for (int s = tid; s <= t; s += 256) ls += __expf(sc[s] - m);
#pragma unroll
    for (int o = 32; o; o >>= 1) ls += __shfl_xor(ls, o, 64);
    if (lane == 0) red2[wave] = ls;
    __syncthreads();
    float inv = 1.f / (red2[0] + red2[1] + red2[2] + red2[3]);
    for (int s = tid; s <= t; s += 256) {
        float a = __expf(sc[s] - m) * inv;
        sc[s] = a;
        scw[(bp * 8 + h) * 512 + s] = a;
    }
    __syncthreads();

    // Phase 3: PV. col = lane; rows strided across waves.
    float acc = 0.f;
    const float* Vp = Vin + (bp * 512) * 512 + h * 64 + lane;
    int s = wave;
    for (; s + 12 < t; s += 16) {
        float v0 = __builtin_nontemporal_load(Vp + (size_t)(s     ) * 512);
        float v1 = __builtin_nontemporal_load(Vp + (size_t)(s +  4) * 512);
        float v2 = __builtin_nontemporal_load(Vp + (size_t)(s +  8) * 512);
        float v3 = __builtin_nontemporal_load(Vp + (size_t)(s + 12) * 512);
        acc += sc[s] * v0 + sc[s + 4] * v1 + sc[s + 8] * v2 + sc[s + 12] * v3;
    }
    for (; s < t; s += 4) acc += sc[s] * __builtin_nontemporal_load(Vp + (size_t)s * 512);
    if ((t & 3) == wave) acc += sc[t] * vws[bp * 512 + h * 64 + lane];
    part[wave][lane] = acc;
    __syncthreads();
    if (tid < 64)
        zh[bp * 512 + h * 64 + tid] = part[0][tid] + part[1][tid] + part[2][tid] + part[3][tid];
}

// ===== z projection: zp = zh @ Wo + bo + SIGMA*eps_z. grid (4,16), 512 thr =====
__global__ __launch_bounds__(512)
void k_zproj(const float* __restrict__ zh, const float* __restrict__ Wo,
             const float* __restrict__ bo, const float* __restrict__ epsz,
             float* __restrict__ out)
{
    int tid = threadIdx.x;
    int col = tid & 127, kq = tid >> 7;
    int colg = blockIdx.x * 128 + col;
    int row0 = blockIdx.y * 8;
    __shared__ float rs[8][512];
#pragma unroll
    for (int p = 0; p < 8; p++) rs[p][tid] = zh[(row0 + p) * 512 + tid];
    __syncthreads();
    float acc[8] = {0,0,0,0,0,0,0,0};
    const float* Wp = Wo + (kq * 128) * 512 + colg;
#pragma unroll 8
    for (int d = 0; d < 128; d++) {
        float wv = Wp[d * 512];
#pragma unroll
        for (int p = 0; p < 8; p++) acc[p] += rs[p][kq * 128 + d] * wv;
    }
    __syncthreads();
    float (*part)[8][128] = (float(*)[8][128])rs;
#pragma unroll
    for (int p = 0; p < 8; p++) part[kq][p][col] = acc[p];
    __syncthreads();
#pragma unroll
    for (int j = 0; j < 2; j++) {
        int idx = tid + j * 512;
        int p = idx >> 7, c = idx & 127;
        int cg = blockIdx.x * 128 + c;
        out[(row0 + p) * 512 + cg] = part[0][p][c] + part[1][p][c] + part[2][p][c] + part[3][p][c]
                                   + bo[cg] + SIGMA * epsz[(row0 + p) * 512 + cg];
    }
}

// ===== layernorm: out = LN(a+b)*g + beta. grid 128, 512 thr =====
__global__ __launch_bounds__(512)
void k_ln(const float* __restrict__ a, const float* __restrict__ b,
          const float* __restrict__ g, const float* __restrict__ beta,
          float* __restrict__ out)
{
    __shared__ float red[8];
    int row = blockIdx.x, tid = threadIdx.x;
    float x = a[row * 512 + tid] + b[row * 512 + tid];
    float s = x;
#pragma unroll
    for (int o = 32; o; o >>= 1) s += __shfl_xor(s, o, 64);
    if ((tid & 63) == 0) red[tid >> 6] = s;
    __syncthreads();
    float tot = 0.f;
#pragma unroll
    for (int i = 0; i < 8; i++) tot += red[i];
    float mu = tot * (1.f / 512.f);
    float dx = x - mu;
    float s2 = dx * dx;
#pragma unroll
    for (int o = 32; o; o >>= 1) s2 += __shfl_xor(s2, o, 64);
    __syncthreads();
    if ((tid & 63) == 0) red[tid >> 6] = s2;
    __syncthreads();
    float tot2 = 0.f;
#pragma unroll
    for (int i = 0; i < 8; i++) tot2 += red[i];
    float var = tot2 * (1.f / 512.f);
    out[row * 512 + tid] = dx * rsqrtf(var + 1e-6f) * g[tid] + beta[tid];
}

// ===== ln3 with ffn2-partial reduction: out = LN(sum(f2p)+b2 + o1) =====
__global__ __launch_bounds__(512)
void k_ln_sum4(const float* __restrict__ f2p, const float* __restrict__ b2,
               const float* __restrict__ o1, const float* __restrict__ g,
               const float* __restrict__ beta, float* __restrict__ out)
{
    __shared__ float red[8];
    int row = blockIdx.x, tid = threadIdx.x;
    int idx = row * 512 + tid;
    float x = f2p[idx] + f2p[65536 + idx] + f2p[131072 + idx] + f2p[196608 + idx]
            + b2[tid] + o1[idx];
    float s = x;
#pragma unroll
    for (int o = 32; o; o >>= 1) s += __shfl_xor(s, o, 64);
    if ((tid & 63) == 0) red[tid >> 6] = s;
    __syncthreads();
    float tot = 0.f;
#pragma unroll
    for (int i = 0; i < 8; i++) tot += red[i];
    float mu = tot * (1.f / 512.f);
    float dx = x - mu;
    float s2 = dx * dx;
#pragma unroll
    for (int o = 32; o; o >>= 1) s2 += __shfl_xor(s2, o, 64);
    __syncthreads();
    if ((tid & 63) == 0) red[tid >> 6] = s2;
    __syncthreads();
    float tot2 = 0.f;
#pragma unroll
    for (int i = 0; i < 8; i++) tot2 += red[i];
    float var = tot2 * (1.f / 512.f);
    out[idx] = dx * rsqrtf(var + 1e-6f) * g[tid] + beta[tid];
}

// ===== ffn1: h1 = relu(o1 @ W1 + b1). grid (16 coltiles, 8 rowgroups of 16), 512 thr =====
__global__ __launch_bounds__(512)
void k_ffn1(const float* __restrict__ in, const float* __restrict__ W1,
            const float* __restrict__ b1, float* __restrict__ h1)
{
    int tid = threadIdx.x;
    int col = tid & 127, kq = tid >> 7;
    int colg = blockIdx.x * 128 + col;
    int row0 = blockIdx.y * 16;
    __shared__ float rs[16][512];
#pragma unroll
    for (int j = 0; j < 16; j++) {
        int idx = tid + j * 512;
        rs[idx >> 9][idx & 511] = in[(row0 + (idx >> 9)) * 512 + (idx & 511)];
    }
    __syncthreads();
    float acc[16];
#pragma unroll
    for (int p = 0; p < 16; p++) acc[p] = 0.f;
    const float* Wp = W1 + (kq * 128) * NDFF + colg;
#pragma unroll 8
    for (int d = 0; d < 128; d++) {
        float wv = Wp[d * NDFF];
#pragma unroll
        for (int p = 0; p < 16; p++) acc[p] += rs[p][kq * 128 + d] * wv;
    }
    __syncthreads();
    float (*part)[16][128] = (float(*)[16][128])rs;
#pragma unroll
    for (int p = 0; p < 16; p++) part[kq][p][col] = acc[p];
    __syncthreads();
#pragma unroll
    for (int j = 0; j < 4; j++) {
        int idx = tid + j * 512;
        int p = idx >> 7, c = idx & 127;
        int cg = blockIdx.x * 128 + c;
        float v = part[0][p][c] + part[1][p][c] + part[2][p][c] + part[3][p][c] + b1[cg];
        h1[(row0 + p) * NDFF + cg] = fmaxf(v, 0.f);
    }
}

// ===== ffn2 partials: grid (4 coltiles, 8 rowgroups of 16, 4 ksect of 512), 512 thr =====
__global__ __launch_bounds__(512)
void k_ffn2p(const float* __restrict__ h1, const float* __restrict__ W2,
             float* __restrict__ f2p)
{
    int tid = threadIdx.x;
    int col = tid & 127, kq = tid >> 7;
    int colg = blockIdx.x * 128 + col;
    int row0 = blockIdx.y * 16;
    int ks = blockIdx.z;
    __shared__ float rs[16][512];
#pragma unroll
    for (int j = 0; j < 16; j++) {
        int idx = tid + j * 512;
        rs[idx >> 9][idx & 511] = h1[(row0 + (idx >> 9)) * NDFF + ks * 512 + (idx & 511)];
    }
    __syncthreads();
    float acc[16];
#pragma unroll
    for (int p = 0; p < 16; p++) acc[p] = 0.f;
    const float* Wp = W2 + (ks * 512 + kq * 128) * 512 + colg;
#pragma unroll 8
    for (int d = 0; d < 128; d++) {
        float wv = Wp[d * 512];
#pragma unroll
        for (int p = 0; p < 16; p++) acc[p] += rs[p][kq * 128 + d] * wv;
    }
    __syncthreads();
    float (*part)[16][128] = (float(*)[16][128])rs;
#pragma unroll
    for (int p = 0; p < 16; p++) part[kq][p][col] = acc[p];
    __syncthreads();
#pragma unroll
    for (int j = 0; j < 4; j++) {
        int idx = tid + j * 512;
        int p = idx >> 7, c = idx & 127;
        int cg = blockIdx.x * 128 + c;
        f2p[ks * 65536 + (row0 + p) * 512 + cg] =
            part[0][p][c] + part[1][p][c] + part[2][p][c] + part[3][p][c];
    }
}

// ===== pred = r_ @ Wout + bout. grid (40 coltiles of 256, 4 rowgroups of 32), 512 thr =====
__global__ __launch_bounds__(512)
void k_pred(const float* __restrict__ r_, const float* __restrict__ Wout,
            const float* __restrict__ bout, float* __restrict__ pred)
{
    int tid = threadIdx.x;
    int col = tid & 255, kh = tid >> 8;
    int colg = blockIdx.x * 256 + col;
    int colL = min(colg, NVOC - 1);
    int row0 = blockIdx.y * 32;
    __shared__ float rs[32][256];
    float acc[32];
#pragma unroll
    for (int p = 0; p < 32; p++) acc[p] = 0.f;
    for (int kc = 0; kc < 2; kc++) {
        __syncthreads();
#pragma unroll
        for (int j = 0; j < 16; j++) {
            int idx = tid + j * 512;
            rs[idx >> 8][idx & 255] = r_[(row0 + (idx >> 8)) * 512 + kc * 256 + (idx & 255)];
        }
        __syncthreads();
        const float* Wp = Wout + (kc * 256 + kh * 128) * NVOC + colL;
#pragma unroll 4
        for (int d = 0; d < 128; d++) {
            float wv = Wp[d * NVOC];
#pragma unroll
            for (int p = 0; p < 32; p++) acc[p] += rs[p][kh * 128 + d] * wv;
        }
    }
    __syncthreads();
    float (*part)[256] = (float(*)[256])rs;
    if (kh == 1) {
#pragma unroll
        for (int p = 0; p < 32; p++) part[p][col] = acc[p];
    }
    __syncthreads();
    if (kh == 0 && colg < NVOC) {
        float bv = bout[colg];
#pragma unroll
        for (int p = 0; p < 32; p++)
            pred[(row0 + p) * NVOC + colg] = acc[p] + part[p][col] + bv;
    }
}

// ===== per-row softmax stats + w_sq + attn_weights output. grid 128, 512 thr =====
__global__ __launch_bounds__(512)
void k_soft(const float* __restrict__ pred, const int* __restrict__ x,
            const float* __restrict__ scw, const int* __restrict__ t_ptr,
            float* __restrict__ rowmax, float* __restrict__ rowsum,
            float* __restrict__ wsq, float* __restrict__ out)
{
    __shared__ float red[8];
    int row = blockIdx.x, tid = threadIdx.x;
    // attn_weights: mean over heads, zero past t
    {
        int t = *t_ptr;
        float a = 0.f;
        if (tid <= t) {
#pragma unroll
            for (int hh = 0; hh < 8; hh++) a += scw[(row * 8 + hh) * 512 + tid];
            a *= 0.125f;
        }
        out[O6 + row * 512 + tid] = a;
    }
    const float* pr = pred + row * NVOC;
    float m = -3.0e38f;
    for (int v = tid; v < NVOC; v += 512) m = fmaxf(m, pr[v]);
#pragma unroll
    for (int o = 32; o; o >>= 1) m = fmaxf(m, __shfl_xor(m, o, 64));
    if ((tid & 63) == 0) red[tid >> 6] = m;
    __syncthreads();
#pragma unroll
    for (int i = 0; i < 8; i++) m = fmaxf(m, red[i]);
    __syncthreads();
    float s = 0.f;
    for (int v = tid; v < NVOC; v += 512) s += __expf(pr[v] - m);
#pragma unroll
    for (int o = 32; o; o >>= 1) s += __shfl_xor(s, o, 64);
    if ((tid & 63) == 0) red[tid >> 6] = s;
    __syncthreads();
    if (tid == 0) {
        float tot = 0.f;
#pragma unroll
        for (int i = 0; i < 8; i++) tot += red[i];
        rowmax[row] = m; rowsum[row] = tot;
        int b = row >> 4;
        float w = __expf(pr[x[b]] - m) / tot;
        wsq[row] = w;
        out[O9 + row] = w;
    }
}

// ===== vocab outputs + it/amw computation. grid (20, 8), 512 thr =====
__global__ __launch_bounds__(512)
void k_vocab(const float* __restrict__ pred, const float* __restrict__ rowmax,
             const float* __restrict__ rowsum, const float* __restrict__ wsq,
             const float* __restrict__ gumbel, int* __restrict__ it,
             float* __restrict__ out)
{
    int b = blockIdx.y;
    int tid = threadIdx.x;
    __shared__ int s_amw;
    if (tid == 0) {
        float bw = -3.0e38f; int bj = 0;
#pragma unroll
        for (int pp = 0; pp < 16; pp++) {
            float wv = wsq[b * 16 + pp];
            if (wv > bw) { bw = wv; bj = pp; }
        }
        s_amw = bj;
    }
    if (blockIdx.x == 0 && tid < 16) {
        float best = -3.0e38f; int bi = 0;
#pragma unroll
        for (int pp = 0; pp < 16; pp++) {
            float v = logf(wsq[b * 16 + pp] + 1e-10f) + gumbel[(b * 16 + tid) * 16 + pp];
            if (v > best) { best = v; bi = pp; }
        }
        it[b * 16 + tid] = bi;
    }
    __syncthreads();
    int v = blockIdx.x * 512 + tid;
    if (v >= NVOC) return;
    int amw = s_amw;
    float ga = 0.f, as = 0.f;
#pragma unroll
    for (int p = 0; p < 16; p++) {
        int rr = b * 16 + p;
        float pv = pred[rr * NVOC + v];
        ga += pv;
        as += __expf(pv - rowmax[rr]) * (1.f / rowsum[rr]);
    }
    out[O3 + b * NVOC + v] = ga * (1.f / 16.f);
    out[O2 + b * NVOC + v] = as * (1.f / 16.f);
    out[O4 + b * NVOC + v] = pred[(b * 16 + amw) * NVOC + v];
}

// ===== K / Vs resample + misc outputs. grid 4096 x 256 grid-stride =====
__global__ __launch_bounds__(256)
void k_resample(const float* __restrict__ Kin, const float* __restrict__ kws,
                const int* __restrict__ it, const int* __restrict__ t_ptr,
                const float* __restrict__ r, const float* __restrict__ epsz,
                const float* __restrict__ zws, const int* __restrict__ Iin,
                float* __restrict__ out)
{
    int t = *t_ptr;
    const f32x4* K4  = (const f32x4*)Kin;
    const f32x4* kw4 = (const f32x4*)kws;
    const f32x4* r4  = (const f32x4*)r;
    const f32x4* e4  = (const f32x4*)epsz;
    const f32x4* z4  = (const f32x4*)zws;
    f32x4* oK = (f32x4*)(out + O7);
    f32x4* oV = (f32x4*)(out + O8);
    const int total = 128 * 512 * 128;      // float4 units of K/Vs
    const int total2 = total + 16384;       // + misc (65536 floats)
    for (int i = blockIdx.x * 256 + threadIdx.x; i < total2; i += gridDim.x * 256) {
        if (i < total) {
            int lane = i & 127;
            int row = i >> 7;
            int s = row & 511;
            int bp = row >> 9;
            int b = bp >> 4;
            f32x4 vK, vV;
            if (s > t) {
                vK = __builtin_nontemporal_load(&K4[i]);
                vV = vK;
            } else {
                int ip = it[bp];
                int ip2 = it[b * 16 + ip];
                if (s == t) {
                    vK = kw4[(b * 16 + ip) * 128 + lane];
                    vV = kw4[(b * 16 + ip2) * 128 + lane];
                } else {
                    vK = K4[((b * 16 + ip) * 512 + s) * 128 + lane];
                    vV = K4[((b * 16 + ip2) * 512 + s) * 128 + lane];
                }
            }
            __builtin_nontemporal_store(vK, &oK[i]);
            __builtin_nontemporal_store(vV, &oV[i]);
        } else {
            int j = i - total;              // 0..16383 float4
            int fidx = j * 4;
            ((f32x4*)(out + O0))[j] = r4[j];
            ((f32x4*)(out + O5))[j] = e4[j];
            int row = fidx >> 9, d0 = fidx & 511;
            int b = row >> 4;
            int ip = it[row];
            ((f32x4*)(out + O1))[j] = z4[((b * 16 + ip) << 7) + (d0 >> 2)];
#pragma unroll
            for (int k = 0; k < 4; k++) {
                int s = d0 + k;
                float iv;
                if (s < t)       iv = (float)Iin[((b * 16 + ip) << 9) + s];
                else if (s == t) iv = (float)ip;
                else             iv = (float)Iin[row * 512 + s];
                out[O10 + fidx + k] = iv;
            }
        }
    }
}

extern "C" void kernel_launch(void* const* d_in, const int* in_sizes, int n_in,
                              void* d_out, int out_size, void* d_ws, size_t ws_size,
                              hipStream_t stream) {
    const float* r      = (const float*)d_in[0];
    const int*   x      = (const int*)d_in[1];
    const float* Kin    = (const float*)d_in[2];
    const float* Vin    = (const float*)d_in[3];
    const int*   Iin    = (const int*)d_in[5];
    const int*   t_ptr  = (const int*)d_in[6];
    const float* eps_q  = (const float*)d_in[7];
    const float* eps_k  = (const float*)d_in[8];
    const float* eps_v  = (const float*)d_in[9];
    const float* eps_z  = (const float*)d_in[10];
    const float* gumbel = (const float*)d_in[11];
    const float* Wq = (const float*)d_in[12]; const float* bq = (const float*)d_in[13];
    const float* Wk = (const float*)d_in[14]; const float* bk = (const float*)d_in[15];
    const float* Wv = (const float*)d_in[16]; const float* bv = (const float*)d_in[17];
    const float* Wo = (const float*)d_in[18]; const float* bo = (const float*)d_in[19];
    const float* ln1_g = (const float*)d_in[20]; const float* ln1_b = (const float*)d_in[21];
    const float* ln3_g = (const float*)d_in[22]; const float* ln3_b = (const float*)d_in[23];
    const float* W1 = (const float*)d_in[24]; const float* b1 = (const float*)d_in[25];
    const float* W2 = (const float*)d_in[26]; const float* b2 = (const float*)d_in[27];
    const float* Wout = (const float*)d_in[28]; const float* bout = (const float*)d_in[29];

    float* ws  = (float*)d_ws;
    float* q   = ws + WQ;
    float* kv  = ws + WK;
    float* vv  = ws + WV;
    float* zh  = ws + WZH;
    float* zp  = ws + WZ;
    float* o1  = ws + WO1;
    float* h1  = ws + WH1;
    float* rr  = ws + WR;
    float* pr  = ws + WPRED;
    float* rmx = ws + WMAX;
    float* rsm = ws + WSUM;
    float* wsq = ws + WWSQ;
    int*   itw = (int*)(ws + WIT);
    float* f2p = ws + WF2P;
    float* scw = ws + WSC;
    float* outp = (float*)d_out;

    k_qkv<<<dim3(4, 16, 3), 512, 0, stream>>>(r, Wq, bq, eps_q, q, Wk, bk, eps_k, kv, Wv, bv, eps_v, vv);
    k_attn<<<dim3(128, 8), 256, 0, stream>>>(q, kv, vv, Kin, Vin, t_ptr, zh, scw);
    k_zproj<<<dim3(4, 16), 512, 0, stream>>>(zh, Wo, bo, eps_z, zp);
    k_ln<<<128, 512, 0, stream>>>(zp, r, ln1_g, ln1_b, o1);
    k_ffn1<<<dim3(16, 8), 512, 0, stream>>>(o1, W1, b1, h1);
    k_ffn2p<<<dim3(4, 8, 4), 512, 0, stream>>>(h1, W2, f2p);
    k_ln_sum4<<<128, 512, 0, stream>>>(f2p, b2, o1, ln3_g, ln3_b, rr);
    k_pred<<<dim3(40, 4), 512, 0, stream>>>(rr, Wout, bout, pr);
    k_soft<<<128, 512, 0, stream>>>(pr, x, scw, t_ptr, rmx, rsm, wsq, outp);
    k_vocab<<<dim3(20, 8), 512, 0, stream>>>(pr, rmx, rsm, wsq, gumbel, itw, outp);
    k_resample<<<4096, 256, 0, stream>>>(Kin, kv, itw, t_ptr, r, eps_z, zp, Iin, outp);
}

// Round 7
// 199.787 us; speedup vs baseline: 1.6181x; 1.3295x over previous
//
#include <hip/hip_runtime.h>

#define NDFF 2048
#define NVOC 10000
#define SIGMA 0.1f

typedef float f32x4 __attribute__((ext_vector_type(4)));

// ---- output offsets (floats) ----
#define O0 0
#define O1 65536
#define O2 131072
#define O3 211072
#define O4 291072
#define O5 371072
#define O6 436608
#define O7 502144
#define O8 34056576
#define O9 67611008
#define O10 67611136

// ---- workspace offsets (floats) ----
#define WQ    0
#define WK    65536
#define WV    131072
#define WZH   196608
#define WZ    262144
#define WO1   327680
#define WH1   393216    // 262144
#define WR    655360
#define WPRED 720896    // 1280000
#define WMAX  2000896
#define WSUM  2001024
#define WWSQ  2001152
#define WIT   2001280
#define WF2P  2001536   // 262144
#define WSC   2263680   // 128 x 8 x 512 normalized attn

// ===== QKV projection: out = r @ W + b + SIGMA*eps =====
// grid (8 coltiles of 64, 16 rowgroups of 8, 3), 512 thr; 8-way K-split
__global__ __launch_bounds__(512)
void k_qkv(const float* __restrict__ r,
           const float* __restrict__ Wq, const float* __restrict__ bq, const float* __restrict__ eq, float* __restrict__ oq,
           const float* __restrict__ Wk, const float* __restrict__ bk, const float* __restrict__ ek, float* __restrict__ ok,
           const float* __restrict__ Wv, const float* __restrict__ bv, const float* __restrict__ ev, float* __restrict__ ov)
{
    const float *W, *bias, *eps; float* out;
    if (blockIdx.z == 0)      { W = Wq; bias = bq; eps = eq; out = oq; }
    else if (blockIdx.z == 1) { W = Wk; bias = bk; eps = ek; out = ok; }
    else                      { W = Wv; bias = bv; eps = ev; out = ov; }
    int tid = threadIdx.x;
    int col = tid & 63, kq = tid >> 6;       // 8-way K-split
    int colg = blockIdx.x * 64 + col;
    int row0 = blockIdx.y * 8;
    __shared__ float rs[8][512];             // 16 KB
#pragma unroll
    for (int j = 0; j < 8; j++) {
        int idx = tid + j * 512;
        rs[idx >> 9][idx & 511] = r[(row0 + (idx >> 9)) * 512 + (idx & 511)];
    }
    __syncthreads();
    float acc[8] = {0,0,0,0,0,0,0,0};
    const float* Wp = W + (kq * 64) * 512 + colg;
#pragma unroll 8
    for (int d = 0; d < 64; d++) {
        float wv = Wp[d * 512];
#pragma unroll
        for (int p = 0; p < 8; p++) acc[p] += rs[p][kq * 64 + d] * wv;
    }
    __syncthreads();
    float (*part)[8][64] = (float(*)[8][64])rs;   // 16 KB reuse
#pragma unroll
    for (int p = 0; p < 8; p++) part[kq][p][col] = acc[p];
    __syncthreads();
    {
        int p = tid >> 6, c = tid & 63;
        int cg = blockIdx.x * 64 + c;
        float v = 0.f;
#pragma unroll
        for (int k = 0; k < 8; k++) v += part[k][p][c];
        out[(row0 + p) * 512 + cg] = v + bias[cg] + SIGMA * eps[(row0 + p) * 512 + cg];
    }
}

// ===== fused attention: scores + softmax + PV per (bp, head) =====
// grid (128, 8), 256 thr.
__global__ __launch_bounds__(256)
void k_attn(const float* __restrict__ qws, const float* __restrict__ kws,
            const float* __restrict__ vws, const float* __restrict__ Kin,
            const float* __restrict__ Vin, const int* __restrict__ t_ptr,
            float* __restrict__ zh, float* __restrict__ scw)
{
    int t = *t_ptr;
    int bp = blockIdx.x, h = blockIdx.y;
    int tid = threadIdx.x;
    int wave = tid >> 6, lane = tid & 63;
    __shared__ float sc[512];
    __shared__ float red[4], red2[4];
    __shared__ float part[4][64];

    float4 qv = ((const float4*)(qws + bp * 512 + h * 64))[lane & 15];

    for (int sb = wave * 4; sb <= t; sb += 16) {
        int s = sb + (lane >> 4);
        bool valid = (s <= t);
        int ss = valid ? s : t;
        const float4* kr = (ss == t) ? (const float4*)(kws + bp * 512 + h * 64)
                                     : (const float4*)(Kin + (bp * 512 + ss) * 512 + h * 64);
        float4 kv = kr[lane & 15];
        float p = qv.x * kv.x + qv.y * kv.y + qv.z * kv.z + qv.w * kv.w;
#pragma unroll
        for (int m = 1; m < 16; m <<= 1) p += __shfl_xor(p, m, 64);
        if ((lane & 15) == 0 && valid) sc[s] = p * 0.125f;
    }
    __syncthreads();

    float lm = -3.0e38f;
    for (int s = tid; s <= t; s += 256) lm = fmaxf(lm, sc[s]);
#pragma unroll
    for (int o = 32; o; o >>= 1) lm = fmaxf(lm, __shfl_xor(lm, o, 64));
    if (lane == 0) red[wave] = lm;
    __syncthreads();
    float m = fmaxf(fmaxf(red[0], red[1]), fmaxf(red[2], red[3]));
    float ls = 0.f;
    for (int s = tid; s <= t; s += 256) ls += __expf(sc[s] - m);
#pragma unroll
    for (int o = 32; o; o >>= 1) ls += __shfl_xor(ls, o, 64);
    if (lane == 0) red2[wave] = ls;
    __syncthreads();
    float inv = 1.f / (red2[0] + red2[1] + red2[2] + red2[3]);
    for (int s = tid; s <= t; s += 256) {
        float a = __expf(sc[s] - m) * inv;
        sc[s] = a;
        scw[(bp * 8 + h) * 512 + s] = a;
    }
    __syncthreads();

    float acc = 0.f;
    const float* Vp = Vin + (bp * 512) * 512 + h * 64 + lane;
    int s = wave;
    for (; s + 12 < t; s += 16) {
        float v0 = __builtin_nontemporal_load(Vp + (size_t)(s     ) * 512);
        float v1 = __builtin_nontemporal_load(Vp + (size_t)(s +  4) * 512);
        float v2 = __builtin_nontemporal_load(Vp + (size_t)(s +  8) * 512);
        float v3 = __builtin_nontemporal_load(Vp + (size_t)(s + 12) * 512);
        acc += sc[s] * v0 + sc[s + 4] * v1 + sc[s + 8] * v2 + sc[s + 12] * v3;
    }
    for (; s < t; s += 4) acc += sc[s] * __builtin_nontemporal_load(Vp + (size_t)s * 512);
    if ((t & 3) == wave) acc += sc[t] * vws[bp * 512 + h * 64 + lane];
    part[wave][lane] = acc;
    __syncthreads();
    if (tid < 64)
        zh[bp * 512 + h * 64 + tid] = part[0][tid] + part[1][tid] + part[2][tid] + part[3][tid];
}

// ===== z projection: zp = zh @ Wo + bo + SIGMA*eps_z =====
// grid (8 coltiles of 64, 16 rowgroups of 8), 512 thr; 8-way K-split
__global__ __launch_bounds__(512)
void k_zproj(const float* __restrict__ zh, const float* __restrict__ Wo,
             const float* __restrict__ bo, const float* __restrict__ epsz,
             float* __restrict__ out)
{
    int tid = threadIdx.x;
    int col = tid & 63, kq = tid >> 6;
    int colg = blockIdx.x * 64 + col;
    int row0 = blockIdx.y * 8;
    __shared__ float rs[8][512];
#pragma unroll
    for (int j = 0; j < 8; j++) {
        int idx = tid + j * 512;
        rs[idx >> 9][idx & 511] = zh[(row0 + (idx >> 9)) * 512 + (idx & 511)];
    }
    __syncthreads();
    float acc[8] = {0,0,0,0,0,0,0,0};
    const float* Wp = Wo + (kq * 64) * 512 + colg;
#pragma unroll 8
    for (int d = 0; d < 64; d++) {
        float wv = Wp[d * 512];
#pragma unroll
        for (int p = 0; p < 8; p++) acc[p] += rs[p][kq * 64 + d] * wv;
    }
    __syncthreads();
    float (*part)[8][64] = (float(*)[8][64])rs;
#pragma unroll
    for (int p = 0; p < 8; p++) part[kq][p][col] = acc[p];
    __syncthreads();
    {
        int p = tid >> 6, c = tid & 63;
        int cg = blockIdx.x * 64 + c;
        float v = 0.f;
#pragma unroll
        for (int k = 0; k < 8; k++) v += part[k][p][c];
        out[(row0 + p) * 512 + cg] = v + bo[cg] + SIGMA * epsz[(row0 + p) * 512 + cg];
    }
}

// ===== layernorm: out = LN(a+b)*g + beta. grid 128, 512 thr =====
__global__ __launch_bounds__(512)
void k_ln(const float* __restrict__ a, const float* __restrict__ b,
          const float* __restrict__ g, const float* __restrict__ beta,
          float* __restrict__ out)
{
    __shared__ float red[8];
    int row = blockIdx.x, tid = threadIdx.x;
    float x = a[row * 512 + tid] + b[row * 512 + tid];
    float s = x;
#pragma unroll
    for (int o = 32; o; o >>= 1) s += __shfl_xor(s, o, 64);
    if ((tid & 63) == 0) red[tid >> 6] = s;
    __syncthreads();
    float tot = 0.f;
#pragma unroll
    for (int i = 0; i < 8; i++) tot += red[i];
    float mu = tot * (1.f / 512.f);
    float dx = x - mu;
    float s2 = dx * dx;
#pragma unroll
    for (int o = 32; o; o >>= 1) s2 += __shfl_xor(s2, o, 64);
    __syncthreads();
    if ((tid & 63) == 0) red[tid >> 6] = s2;
    __syncthreads();
    float tot2 = 0.f;
#pragma unroll
    for (int i = 0; i < 8; i++) tot2 += red[i];
    float var = tot2 * (1.f / 512.f);
    out[row * 512 + tid] = dx * rsqrtf(var + 1e-6f) * g[tid] + beta[tid];
}

// ===== ln3 with ffn2-partial reduction: out = LN(sum(f2p)+b2 + o1) =====
__global__ __launch_bounds__(512)
void k_ln_sum4(const float* __restrict__ f2p, const float* __restrict__ b2,
               const float* __restrict__ o1, const float* __restrict__ g,
               const float* __restrict__ beta, float* __restrict__ out)
{
    __shared__ float red[8];
    int row = blockIdx.x, tid = threadIdx.x;
    int idx = row * 512 + tid;
    float x = f2p[idx] + f2p[65536 + idx] + f2p[131072 + idx] + f2p[196608 + idx]
            + b2[tid] + o1[idx];
    float s = x;
#pragma unroll
    for (int o = 32; o; o >>= 1) s += __shfl_xor(s, o, 64);
    if ((tid & 63) == 0) red[tid >> 6] = s;
    __syncthreads();
    float tot = 0.f;
#pragma unroll
    for (int i = 0; i < 8; i++) tot += red[i];
    float mu = tot * (1.f / 512.f);
    float dx = x - mu;
    float s2 = dx * dx;
#pragma unroll
    for (int o = 32; o; o >>= 1) s2 += __shfl_xor(s2, o, 64);
    __syncthreads();
    if ((tid & 63) == 0) red[tid >> 6] = s2;
    __syncthreads();
    float tot2 = 0.f;
#pragma unroll
    for (int i = 0; i < 8; i++) tot2 += red[i];
    float var = tot2 * (1.f / 512.f);
    out[idx] = dx * rsqrtf(var + 1e-6f) * g[tid] + beta[tid];
}

// ===== ffn1: h1 = relu(o1 @ W1 + b1) =====
// grid (32 coltiles of 64, 16 rowgroups of 8), 512 thr; 8-way K-split
__global__ __launch_bounds__(512)
void k_ffn1(const float* __restrict__ in, const float* __restrict__ W1,
            const float* __restrict__ b1, float* __restrict__ h1)
{
    int tid = threadIdx.x;
    int col = tid & 63, kq = tid >> 6;
    int colg = blockIdx.x * 64 + col;
    int row0 = blockIdx.y * 8;
    __shared__ float rs[8][512];
#pragma unroll
    for (int j = 0; j < 8; j++) {
        int idx = tid + j * 512;
        rs[idx >> 9][idx & 511] = in[(row0 + (idx >> 9)) * 512 + (idx & 511)];
    }
    __syncthreads();
    float acc[8] = {0,0,0,0,0,0,0,0};
    const float* Wp = W1 + (kq * 64) * NDFF + colg;
#pragma unroll 8
    for (int d = 0; d < 64; d++) {
        float wv = Wp[d * NDFF];
#pragma unroll
        for (int p = 0; p < 8; p++) acc[p] += rs[p][kq * 64 + d] * wv;
    }
    __syncthreads();
    float (*part)[8][64] = (float(*)[8][64])rs;
#pragma unroll
    for (int p = 0; p < 8; p++) part[kq][p][col] = acc[p];
    __syncthreads();
    {
        int p = tid >> 6, c = tid & 63;
        int cg = blockIdx.x * 64 + c;
        float v = 0.f;
#pragma unroll
        for (int k = 0; k < 8; k++) v += part[k][p][c];
        h1[(row0 + p) * NDFF + cg] = fmaxf(v + b1[cg], 0.f);
    }
}

// ===== ffn2 partials: grid (8 coltiles of 64, 16 rowgroups, 4 ksect), 512 thr =====
__global__ __launch_bounds__(512)
void k_ffn2p(const float* __restrict__ h1, const float* __restrict__ W2,
             float* __restrict__ f2p)
{
    int tid = threadIdx.x;
    int col = tid & 63, kq = tid >> 6;
    int colg = blockIdx.x * 64 + col;
    int row0 = blockIdx.y * 8;
    int ks = blockIdx.z;
    __shared__ float rs[8][512];
#pragma unroll
    for (int j = 0; j < 8; j++) {
        int idx = tid + j * 512;
        rs[idx >> 9][idx & 511] = h1[(row0 + (idx >> 9)) * NDFF + ks * 512 + (idx & 511)];
    }
    __syncthreads();
    float acc[8] = {0,0,0,0,0,0,0,0};
    const float* Wp = W2 + (ks * 512 + kq * 64) * 512 + colg;
#pragma unroll 8
    for (int d = 0; d < 64; d++) {
        float wv = Wp[d * 512];
#pragma unroll
        for (int p = 0; p < 8; p++) acc[p] += rs[p][kq * 64 + d] * wv;
    }
    __syncthreads();
    float (*part)[8][64] = (float(*)[8][64])rs;
#pragma unroll
    for (int p = 0; p < 8; p++) part[kq][p][col] = acc[p];
    __syncthreads();
    {
        int p = tid >> 6, c = tid & 63;
        int cg = blockIdx.x * 64 + c;
        float v = 0.f;
#pragma unroll
        for (int k = 0; k < 8; k++) v += part[k][p][c];
        f2p[ks * 65536 + (row0 + p) * 512 + cg] = v;
    }
}

// ===== pred = r_ @ Wout + bout. grid (40 coltiles of 256, 8 rowgroups of 16), 512 thr =====
__global__ __launch_bounds__(512)
void k_pred(const float* __restrict__ r_, const float* __restrict__ Wout,
            const float* __restrict__ bout, float* __restrict__ pred)
{
    int tid = threadIdx.x;
    int col = tid & 255, kh = tid >> 8;      // 2-way K-split (256 each)
    int colg = blockIdx.x * 256 + col;
    int colL = min(colg, NVOC - 1);
    int row0 = blockIdx.y * 16;
    __shared__ float rs[16][512];            // 32 KB
#pragma unroll
    for (int j = 0; j < 16; j++) {
        int idx = tid + j * 512;
        rs[idx >> 9][idx & 511] = r_[(row0 + (idx >> 9)) * 512 + (idx & 511)];
    }
    __syncthreads();
    float acc[16];
#pragma unroll
    for (int p = 0; p < 16; p++) acc[p] = 0.f;
    const float* Wp = Wout + (kh * 256) * NVOC + colL;
#pragma unroll 4
    for (int d = 0; d < 256; d++) {
        float wv = Wp[d * NVOC];
#pragma unroll
        for (int p = 0; p < 16; p++) acc[p] += rs[p][kh * 256 + d] * wv;
    }
    __syncthreads();
    float (*part)[256] = (float(*)[256])rs;  // 16 KB reuse
    if (kh == 1) {
#pragma unroll
        for (int p = 0; p < 16; p++) part[p][col] = acc[p];
    }
    __syncthreads();
    if (kh == 0 && colg < NVOC) {
        float bv = bout[colg];
#pragma unroll
        for (int p = 0; p < 16; p++)
            pred[(row0 + p) * NVOC + colg] = acc[p] + part[p][col] + bv;
    }
}

// ===== per-row softmax stats + w_sq + attn_weights output. grid 128, 512 thr =====
__global__ __launch_bounds__(512)
void k_soft(const float* __restrict__ pred, const int* __restrict__ x,
            const float* __restrict__ scw, const int* __restrict__ t_ptr,
            float* __restrict__ rowmax, float* __restrict__ rowsum,
            float* __restrict__ wsq, float* __restrict__ out)
{
    __shared__ float red[8];
    int row = blockIdx.x, tid = threadIdx.x;
    {
        int t = *t_ptr;
        float a = 0.f;
        if (tid <= t) {
#pragma unroll
            for (int hh = 0; hh < 8; hh++) a += scw[(row * 8 + hh) * 512 + tid];
            a *= 0.125f;
        }
        out[O6 + row * 512 + tid] = a;
    }
    const float* pr = pred + row * NVOC;
    float m = -3.0e38f;
    for (int v = tid; v < NVOC; v += 512) m = fmaxf(m, pr[v]);
#pragma unroll
    for (int o = 32; o; o >>= 1) m = fmaxf(m, __shfl_xor(m, o, 64));
    if ((tid & 63) == 0) red[tid >> 6] = m;
    __syncthreads();
#pragma unroll
    for (int i = 0; i < 8; i++) m = fmaxf(m, red[i]);
    __syncthreads();
    float s = 0.f;
    for (int v = tid; v < NVOC; v += 512) s += __expf(pr[v] - m);
#pragma unroll
    for (int o = 32; o; o >>= 1) s += __shfl_xor(s, o, 64);
    if ((tid & 63) == 0) red[tid >> 6] = s;
    __syncthreads();
    if (tid == 0) {
        float tot = 0.f;
#pragma unroll
        for (int i = 0; i < 8; i++) tot += red[i];
        rowmax[row] = m; rowsum[row] = tot;
        int b = row >> 4;
        float w = __expf(pr[x[b]] - m) / tot;
        wsq[row] = w;
        out[O9 + row] = w;
    }
}

// ===== vocab outputs + it/amw computation. grid (20, 8), 512 thr =====
__global__ __launch_bounds__(512)
void k_vocab(const float* __restrict__ pred, const float* __restrict__ rowmax,
             const float* __restrict__ rowsum, const float* __restrict__ wsq,
             const float* __restrict__ gumbel, int* __restrict__ it,
             float* __restrict__ out)
{
    int b = blockIdx.y;
    int tid = threadIdx.x;
    __shared__ int s_amw;
    if (tid == 0) {
        float bw = -3.0e38f; int bj = 0;
#pragma unroll
        for (int pp = 0; pp < 16; pp++) {
            float wv = wsq[b * 16 + pp];
            if (wv > bw) { bw = wv; bj = pp; }
        }
        s_amw = bj;
    }
    if (blockIdx.x == 0 && tid < 16) {
        float best = -3.0e38f; int bi = 0;
#pragma unroll
        for (int pp = 0; pp < 16; pp++) {
            float v = logf(wsq[b * 16 + pp] + 1e-10f) + gumbel[(b * 16 + tid) * 16 + pp];
            if (v > best) { best = v; bi = pp; }
        }
        it[b * 16 + tid] = bi;
    }
    __syncthreads();
    int v = blockIdx.x * 512 + tid;
    if (v >= NVOC) return;
    int amw = s_amw;
    float ga = 0.f, as = 0.f;
#pragma unroll
    for (int p = 0; p < 16; p++) {
        int rr = b * 16 + p;
        float pv = pred[rr * NVOC + v];
        ga += pv;
        as += __expf(pv - rowmax[rr]) * (1.f / rowsum[rr]);
    }
    out[O3 + b * NVOC + v] = ga * (1.f / 16.f);
    out[O2 + b * NVOC + v] = as * (1.f / 16.f);
    out[O4 + b * NVOC + v] = pred[(b * 16 + amw) * NVOC + v];
}

// ===== K / Vs resample + misc outputs. grid 4096 x 256 grid-stride =====
__global__ __launch_bounds__(256)
void k_resample(const float* __restrict__ Kin, const float* __restrict__ kws,
                const int* __restrict__ it, const int* __restrict__ t_ptr,
                const float* __restrict__ r, const float* __restrict__ epsz,
                const float* __restrict__ zws, const int* __restrict__ Iin,
                float* __restrict__ out)
{
    int t = *t_ptr;
    const f32x4* K4  = (const f32x4*)Kin;
    const f32x4* kw4 = (const f32x4*)kws;
    const f32x4* r4  = (const f32x4*)r;
    const f32x4* e4  = (const f32x4*)epsz;
    const f32x4* z4  = (const f32x4*)zws;
    f32x4* oK = (f32x4*)(out + O7);
    f32x4* oV = (f32x4*)(out + O8);
    const int total = 128 * 512 * 128;
    const int total2 = total + 16384;
    for (int i = blockIdx.x * 256 + threadIdx.x; i < total2; i += gridDim.x * 256) {
        if (i < total) {
            int lane = i & 127;
            int row = i >> 7;
            int s = row & 511;
            int bp = row >> 9;
            int b = bp >> 4;
            f32x4 vK, vV;
            if (s > t) {
                vK = __builtin_nontemporal_load(&K4[i]);
                vV = vK;
            } else {
                int ip = it[bp];
                int ip2 = it[b * 16 + ip];
                if (s == t) {
                    vK = kw4[(b * 16 + ip) * 128 + lane];
                    vV = kw4[(b * 16 + ip2) * 128 + lane];
                } else {
                    vK = K4[((b * 16 + ip) * 512 + s) * 128 + lane];
                    vV = K4[((b * 16 + ip2) * 512 + s) * 128 + lane];
                }
            }
            __builtin_nontemporal_store(vK, &oK[i]);
            __builtin_nontemporal_store(vV, &oV[i]);
        } else {
            int j = i - total;
            int fidx = j * 4;
            ((f32x4*)(out + O0))[j] = r4[j];
            ((f32x4*)(out + O5))[j] = e4[j];
            int row = fidx >> 9, d0 = fidx & 511;
            int b = row >> 4;
            int ip = it[row];
            ((f32x4*)(out + O1))[j] = z4[((b * 16 + ip) << 7) + (d0 >> 2)];
#pragma unroll
            for (int k = 0; k < 4; k++) {
                int s = d0 + k;
                float iv;
                if (s < t)       iv = (float)Iin[((b * 16 + ip) << 9) + s];
                else if (s == t) iv = (float)ip;
                else             iv = (float)Iin[row * 512 + s];
                out[O10 + fidx + k] = iv;
            }
        }
    }
}

extern "C" void kernel_launch(void* const* d_in, const int* in_sizes, int n_in,
                              void* d_out, int out_size, void* d_ws, size_t ws_size,
                              hipStream_t stream) {
    const float* r      = (const float*)d_in[0];
    const int*   x      = (const int*)d_in[1];
    const float* Kin    = (const float*)d_in[2];
    const float* Vin    = (const float*)d_in[3];
    const int*   Iin    = (const int*)d_in[5];
    const int*   t_ptr  = (const int*)d_in[6];
    const float* eps_q  = (const float*)d_in[7];
    const float* eps_k  = (const float*)d_in[8];
    const float* eps_v  = (const float*)d_in[9];
    const float* eps_z  = (const float*)d_in[10];
    const float* gumbel = (const float*)d_in[11];
    const float* Wq = (const float*)d_in[12]; const float* bq = (const float*)d_in[13];
    const float* Wk = (const float*)d_in[14]; const float* bk = (const float*)d_in[15];
    const float* Wv = (const float*)d_in[16]; const float* bv = (const float*)d_in[17];
    const float* Wo = (const float*)d_in[18]; const float* bo = (const float*)d_in[19];
    const float* ln1_g = (const float*)d_in[20]; const float* ln1_b = (const float*)d_in[21];
    const float* ln3_g = (const float*)d_in[22]; const float* ln3_b = (const float*)d_in[23];
    const float* W1 = (const float*)d_in[24]; const float* b1 = (const float*)d_in[25];
    const float* W2 = (const float*)d_in[26]; const float* b2 = (const float*)d_in[27];
    const float* Wout = (const float*)d_in[28]; const float* bout = (const float*)d_in[29];

    float* ws  = (float*)d_ws;
    float* q   = ws + WQ;
    float* kv  = ws + WK;
    float* vv  = ws + WV;
    float* zh  = ws + WZH;
    float* zp  = ws + WZ;
    float* o1  = ws + WO1;
    float* h1  = ws + WH1;
    float* rr  = ws + WR;
    float* pr  = ws + WPRED;
    float* rmx = ws + WMAX;
    float* rsm = ws + WSUM;
    float* wsq = ws + WWSQ;
    int*   itw = (int*)(ws + WIT);
    float* f2p = ws + WF2P;
    float* scw = ws + WSC;
    float* outp = (float*)d_out;

    k_qkv<<<dim3(8, 16, 3), 512, 0, stream>>>(r, Wq, bq, eps_q, q, Wk, bk, eps_k, kv, Wv, bv, eps_v, vv);
    k_attn<<<dim3(128, 8), 256, 0, stream>>>(q, kv, vv, Kin, Vin, t_ptr, zh, scw);
    k_zproj<<<dim3(8, 16), 512, 0, stream>>>(zh, Wo, bo, eps_z, zp);
    k_ln<<<128, 512, 0, stream>>>(zp, r, ln1_g, ln1_b, o1);
    k_ffn1<<<dim3(32, 16), 512, 0, stream>>>(o1, W1, b1, h1);
    k_ffn2p<<<dim3(8, 16, 4), 512, 0, stream>>>(h1, W2, f2p);
    k_ln_sum4<<<128, 512, 0, stream>>>(f2p, b2, o1, ln3_g, ln3_b, rr);
    k_pred<<<dim3(40, 8), 512, 0, stream>>>(rr, Wout, bout, pr);
    k_soft<<<128, 512, 0, stream>>>(pr, x, scw, t_ptr, rmx, rsm, wsq, outp);
    k_vocab<<<dim3(20, 8), 512, 0, stream>>>(pr, rmx, rsm, wsq, gumbel, itw, outp);
    k_resample<<<4096, 256, 0, stream>>>(Kin, kv, itw, t_ptr, r, eps_z, zp, Iin, outp);
}

// Round 8
// 199.348 us; speedup vs baseline: 1.6216x; 1.0022x over previous
//
#include <hip/hip_runtime.h>

#define NDFF 2048
#define NVOC 10000
#define SIGMA 0.1f

typedef float f32x4 __attribute__((ext_vector_type(4)));

// ---- output offsets (floats) ----
#define O0 0
#define O1 65536
#define O2 131072
#define O3 211072
#define O4 291072
#define O5 371072
#define O6 436608
#define O7 502144
#define O8 34056576
#define O9 67611008
#define O10 67611136

// ---- workspace offsets (floats) ----
#define WQ    0
#define WK    65536
#define WV    131072
#define WZH   196608
#define WZ    262144
#define WO1   327680
#define WH1   393216    // 262144
#define WPRED 720896    // 1280000
#define WMAX  2000896
#define WSUM  2001024
#define WWSQ  2001152
#define WIT   2001280
#define WF2P  2001536   // 262144
#define WSC   2263680   // 128 x 8 x 512 normalized attn

// ===== QKV projection: out = r @ W + b + SIGMA*eps =====
// grid (8 coltiles of 64, 16 rowgroups of 8, 3), 512 thr; 8-way K-split
__global__ __launch_bounds__(512)
void k_qkv(const float* __restrict__ r,
           const float* __restrict__ Wq, const float* __restrict__ bq, const float* __restrict__ eq, float* __restrict__ oq,
           const float* __restrict__ Wk, const float* __restrict__ bk, const float* __restrict__ ek, float* __restrict__ ok,
           const float* __restrict__ Wv, const float* __restrict__ bv, const float* __restrict__ ev, float* __restrict__ ov)
{
    const float *W, *bias, *eps; float* out;
    if (blockIdx.z == 0)      { W = Wq; bias = bq; eps = eq; out = oq; }
    else if (blockIdx.z == 1) { W = Wk; bias = bk; eps = ek; out = ok; }
    else                      { W = Wv; bias = bv; eps = ev; out = ov; }
    int tid = threadIdx.x;
    int col = tid & 63, kq = tid >> 6;
    int colg = blockIdx.x * 64 + col;
    int row0 = blockIdx.y * 8;
    __shared__ float rs[8][512];
#pragma unroll
    for (int j = 0; j < 8; j++) rs[j][tid & 511] = r[(row0 + j) * 512 + tid];
    __syncthreads();
    float acc[8] = {0,0,0,0,0,0,0,0};
    const float* Wp = W + (kq * 64) * 512 + colg;
#pragma unroll 8
    for (int d = 0; d < 64; d++) {
        float wv = Wp[d * 512];
#pragma unroll
        for (int p = 0; p < 8; p++) acc[p] += rs[p][kq * 64 + d] * wv;
    }
    __syncthreads();
    float (*part)[8][64] = (float(*)[8][64])rs;
#pragma unroll
    for (int p = 0; p < 8; p++) part[kq][p][col] = acc[p];
    __syncthreads();
    {
        int p = tid >> 6, c = tid & 63;
        int cg = blockIdx.x * 64 + c;
        float v = 0.f;
#pragma unroll
        for (int k = 0; k < 8; k++) v += part[k][p][c];
        out[(row0 + p) * 512 + cg] = v + bias[cg] + SIGMA * eps[(row0 + p) * 512 + cg];
    }
}

// ===== fused attention: scores + softmax + PV per (bp, head) =====
// grid (128, 8), 512 thr (8 waves).
__global__ __launch_bounds__(512)
void k_attn(const float* __restrict__ qws, const float* __restrict__ kws,
            const float* __restrict__ vws, const float* __restrict__ Kin,
            const float* __restrict__ Vin, const int* __restrict__ t_ptr,
            float* __restrict__ zh, float* __restrict__ scw)
{
    int t = *t_ptr;
    int bp = blockIdx.x, h = blockIdx.y;
    int tid = threadIdx.x;
    int wave = tid >> 6, lane = tid & 63;
    __shared__ float sc[512];
    __shared__ float red[8], red2[8];
    __shared__ float part[8][64];

    float4 qv = ((const float4*)(qws + bp * 512 + h * 64))[lane & 15];

    // Phase 1: scores. 16-lane groups own one s; 8 waves x 4 s per iter.
    for (int sb = wave * 4; sb <= t; sb += 32) {
        int s = sb + (lane >> 4);
        bool valid = (s <= t);
        int ss = valid ? s : t;
        const float4* kr = (ss == t) ? (const float4*)(kws + bp * 512 + h * 64)
                                     : (const float4*)(Kin + (bp * 512 + ss) * 512 + h * 64);
        float4 kv = kr[lane & 15];
        float p = qv.x * kv.x + qv.y * kv.y + qv.z * kv.z + qv.w * kv.w;
#pragma unroll
        for (int m = 1; m < 16; m <<= 1) p += __shfl_xor(p, m, 64);
        if ((lane & 15) == 0 && valid) sc[s] = p * 0.125f;
    }
    __syncthreads();

    // Phase 2: softmax over sc[0..t]
    float lm = -3.0e38f;
    for (int s = tid; s <= t; s += 512) lm = fmaxf(lm, sc[s]);
#pragma unroll
    for (int o = 32; o; o >>= 1) lm = fmaxf(lm, __shfl_xor(lm, o, 64));
    if (lane == 0) red[wave] = lm;
    __syncthreads();
    float m = red[0];
#pragma unroll
    for (int i = 1; i < 8; i++) m = fmaxf(m, red[i]);
    float ls = 0.f;
    for (int s = tid; s <= t; s += 512) ls += __expf(sc[s] - m);
#pragma unroll
    for (int o = 32; o; o >>= 1) ls += __shfl_xor(ls, o, 64);
    if (lane == 0) red2[wave] = ls;
    __syncthreads();
    float tot = 0.f;
#pragma unroll
    for (int i = 0; i < 8; i++) tot += red2[i];
    float inv = 1.f / tot;
    for (int s = tid; s <= t; s += 512) {
        float a = __expf(sc[s] - m) * inv;
        sc[s] = a;
        scw[(bp * 8 + h) * 512 + s] = a;
    }
    __syncthreads();

    // Phase 3: PV. col = lane; rows strided across 8 waves.
    float acc = 0.f;
    const float* Vp = Vin + (bp * 512) * 512 + h * 64 + lane;
    int s = wave;
    for (; s + 24 < t; s += 32) {
        float v0 = __builtin_nontemporal_load(Vp + (size_t)(s     ) * 512);
        float v1 = __builtin_nontemporal_load(Vp + (size_t)(s +  8) * 512);
        float v2 = __builtin_nontemporal_load(Vp + (size_t)(s + 16) * 512);
        float v3 = __builtin_nontemporal_load(Vp + (size_t)(s + 24) * 512);
        acc += sc[s] * v0 + sc[s + 8] * v1 + sc[s + 16] * v2 + sc[s + 24] * v3;
    }
    for (; s < t; s += 8) acc += sc[s] * __builtin_nontemporal_load(Vp + (size_t)s * 512);
    if ((t & 7) == wave) acc += sc[t] * vws[bp * 512 + h * 64 + lane];
    part[wave][lane] = acc;
    __syncthreads();
    if (tid < 64) {
        float v = 0.f;
#pragma unroll
        for (int k = 0; k < 8; k++) v += part[k][tid];
        zh[bp * 512 + h * 64 + tid] = v;
    }
}

// ===== z projection: zp = zh @ Wo + bo + SIGMA*eps_z =====
// grid (8 coltiles of 64, 16 rowgroups of 8), 512 thr; 8-way K-split
__global__ __launch_bounds__(512)
void k_zproj(const float* __restrict__ zh, const float* __restrict__ Wo,
             const float* __restrict__ bo, const float* __restrict__ epsz,
             float* __restrict__ out)
{
    int tid = threadIdx.x;
    int col = tid & 63, kq = tid >> 6;
    int colg = blockIdx.x * 64 + col;
    int row0 = blockIdx.y * 8;
    __shared__ float rs[8][512];
#pragma unroll
    for (int j = 0; j < 8; j++) rs[j][tid] = zh[(row0 + j) * 512 + tid];
    __syncthreads();
    float acc[8] = {0,0,0,0,0,0,0,0};
    const float* Wp = Wo + (kq * 64) * 512 + colg;
#pragma unroll 8
    for (int d = 0; d < 64; d++) {
        float wv = Wp[d * 512];
#pragma unroll
        for (int p = 0; p < 8; p++) acc[p] += rs[p][kq * 64 + d] * wv;
    }
    __syncthreads();
    float (*part)[8][64] = (float(*)[8][64])rs;
#pragma unroll
    for (int p = 0; p < 8; p++) part[kq][p][col] = acc[p];
    __syncthreads();
    {
        int p = tid >> 6, c = tid & 63;
        int cg = blockIdx.x * 64 + c;
        float v = 0.f;
#pragma unroll
        for (int k = 0; k < 8; k++) v += part[k][p][c];
        out[(row0 + p) * 512 + cg] = v + bo[cg] + SIGMA * epsz[(row0 + p) * 512 + cg];
    }
}

// ===== ffn1 with fused LN1: h1 = relu(LN(zp+r) @ W1 + b1); coltile0 writes o1 =====
// grid (32 coltiles of 64, 16 rowgroups of 8), 512 thr; 8-way K-split
__global__ __launch_bounds__(512)
void k_ffn1(const float* __restrict__ zp, const float* __restrict__ r,
            const float* __restrict__ g, const float* __restrict__ be,
            const float* __restrict__ W1, const float* __restrict__ b1,
            float* __restrict__ o1, float* __restrict__ h1)
{
    int tid = threadIdx.x;
    int col = tid & 63, kq = tid >> 6;
    int colg = blockIdx.x * 64 + col;
    int row0 = blockIdx.y * 8;
    __shared__ float rs[8][512];
    __shared__ float sm[8], si[8];
    int wave = tid >> 6, lane = tid & 63;
#pragma unroll
    for (int j = 0; j < 8; j++) {
        int gi = (row0 + j) * 512 + tid;
        rs[j][tid] = zp[gi] + r[gi];
    }
    __syncthreads();
    // LN stats: wave w -> row w
    {
        float s = 0.f;
        for (int c = lane; c < 512; c += 64) s += rs[wave][c];
#pragma unroll
        for (int o = 32; o; o >>= 1) s += __shfl_xor(s, o, 64);
        float mu = s * (1.f / 512.f);
        float v = 0.f;
        for (int c = lane; c < 512; c += 64) { float dx = rs[wave][c] - mu; v += dx * dx; }
#pragma unroll
        for (int o = 32; o; o >>= 1) v += __shfl_xor(v, o, 64);
        if (lane == 0) { sm[wave] = mu; si[wave] = rsqrtf(v * (1.f / 512.f) + 1e-6f); }
    }
    __syncthreads();
#pragma unroll
    for (int j = 0; j < 8; j++) {
        float val = (rs[j][tid] - sm[j]) * si[j] * g[tid] + be[tid];
        rs[j][tid] = val;
        if (blockIdx.x == 0) o1[(row0 + j) * 512 + tid] = val;
    }
    __syncthreads();
    float acc[8] = {0,0,0,0,0,0,0,0};
    const float* Wp = W1 + (kq * 64) * NDFF + colg;
#pragma unroll 8
    for (int d = 0; d < 64; d++) {
        float wv = Wp[d * NDFF];
#pragma unroll
        for (int p = 0; p < 8; p++) acc[p] += rs[p][kq * 64 + d] * wv;
    }
    __syncthreads();
    float (*part)[8][64] = (float(*)[8][64])rs;
#pragma unroll
    for (int p = 0; p < 8; p++) part[kq][p][col] = acc[p];
    __syncthreads();
    {
        int p = tid >> 6, c = tid & 63;
        int cg = blockIdx.x * 64 + c;
        float v = 0.f;
#pragma unroll
        for (int k = 0; k < 8; k++) v += part[k][p][c];
        h1[(row0 + p) * NDFF + cg] = fmaxf(v + b1[cg], 0.f);
    }
}

// ===== ffn2 partials: grid (8 coltiles of 64, 16 rowgroups, 4 ksect), 512 thr =====
__global__ __launch_bounds__(512)
void k_ffn2p(const float* __restrict__ h1, const float* __restrict__ W2,
             float* __restrict__ f2p)
{
    int tid = threadIdx.x;
    int col = tid & 63, kq = tid >> 6;
    int colg = blockIdx.x * 64 + col;
    int row0 = blockIdx.y * 8;
    int ks = blockIdx.z;
    __shared__ float rs[8][512];
#pragma unroll
    for (int j = 0; j < 8; j++)
        rs[j][tid] = h1[(row0 + j) * NDFF + ks * 512 + tid];
    __syncthreads();
    float acc[8] = {0,0,0,0,0,0,0,0};
    const float* Wp = W2 + (ks * 512 + kq * 64) * 512 + colg;
#pragma unroll 8
    for (int d = 0; d < 64; d++) {
        float wv = Wp[d * 512];
#pragma unroll
        for (int p = 0; p < 8; p++) acc[p] += rs[p][kq * 64 + d] * wv;
    }
    __syncthreads();
    float (*part)[8][64] = (float(*)[8][64])rs;
#pragma unroll
    for (int p = 0; p < 8; p++) part[kq][p][col] = acc[p];
    __syncthreads();
    {
        int p = tid >> 6, c = tid & 63;
        int cg = blockIdx.x * 64 + c;
        float v = 0.f;
#pragma unroll
        for (int k = 0; k < 8; k++) v += part[k][p][c];
        f2p[ks * 65536 + (row0 + p) * 512 + cg] = v;
    }
}

// ===== pred with fused LN3: pred = LN(sum4(f2p)+b2+o1) @ Wout + bout =====
// grid (40 coltiles of 256, 8 rowgroups of 16), 512 thr; 2-way K-split
__global__ __launch_bounds__(512)
void k_pred(const float* __restrict__ f2p, const float* __restrict__ b2,
            const float* __restrict__ o1, const float* __restrict__ g3,
            const float* __restrict__ b3, const float* __restrict__ Wout,
            const float* __restrict__ bout, float* __restrict__ pred)
{
    int tid = threadIdx.x;
    int col = tid & 255, kh = tid >> 8;
    int colg = blockIdx.x * 256 + col;
    int colL = min(colg, NVOC - 1);
    int row0 = blockIdx.y * 16;
    __shared__ float rs[16][512];            // 32 KB
    __shared__ float sm[16], si[16];
    int wave = tid >> 6, lane = tid & 63;
#pragma unroll
    for (int j = 0; j < 16; j++) {
        int gi = (row0 + j) * 512 + tid;
        rs[j][tid] = f2p[gi] + f2p[65536 + gi] + f2p[131072 + gi] + f2p[196608 + gi]
                   + b2[tid] + o1[gi];
    }
    __syncthreads();
    // LN stats: wave w -> rows 2w + (lane>>5); 32-lane halves
    {
        int row = wave * 2 + (lane >> 5);
        int l = lane & 31;
        float s = 0.f;
        for (int c = l; c < 512; c += 32) s += rs[row][c];
#pragma unroll
        for (int o = 16; o; o >>= 1) s += __shfl_xor(s, o, 64);
        float mu = s * (1.f / 512.f);
        float v = 0.f;
        for (int c = l; c < 512; c += 32) { float dx = rs[row][c] - mu; v += dx * dx; }
#pragma unroll
        for (int o = 16; o; o >>= 1) v += __shfl_xor(v, o, 64);
        if (l == 0) { sm[row] = mu; si[row] = rsqrtf(v * (1.f / 512.f) + 1e-6f); }
    }
    __syncthreads();
#pragma unroll
    for (int j = 0; j < 16; j++)
        rs[j][tid] = (rs[j][tid] - sm[j]) * si[j] * g3[tid] + b3[tid];
    __syncthreads();
    float acc[16];
#pragma unroll
    for (int p = 0; p < 16; p++) acc[p] = 0.f;
    const float* Wp = Wout + (kh * 256) * NVOC + colL;
#pragma unroll 4
    for (int d = 0; d < 256; d++) {
        float wv = Wp[d * NVOC];
#pragma unroll
        for (int p = 0; p < 16; p++) acc[p] += rs[p][kh * 256 + d] * wv;
    }
    __syncthreads();
    float (*part)[256] = (float(*)[256])rs;  // reuse (16 KB)
    if (kh == 1) {
#pragma unroll
        for (int p = 0; p < 16; p++) part[p][col] = acc[p];
    }
    __syncthreads();
    if (kh == 0 && colg < NVOC) {
        float bv = bout[colg];
#pragma unroll
        for (int p = 0; p < 16; p++)
            pred[(row0 + p) * NVOC + colg] = acc[p] + part[p][col] + bv;
    }
}

// ===== per-row softmax stats + w_sq + attn_weights output. grid 128, 512 thr =====
__global__ __launch_bounds__(512)
void k_soft(const float* __restrict__ pred, const int* __restrict__ x,
            const float* __restrict__ scw, const int* __restrict__ t_ptr,
            float* __restrict__ rowmax, float* __restrict__ rowsum,
            float* __restrict__ wsq, float* __restrict__ out)
{
    __shared__ float red[8];
    int row = blockIdx.x, tid = threadIdx.x;
    {
        int t = *t_ptr;
        float a = 0.f;
        if (tid <= t) {
#pragma unroll
            for (int hh = 0; hh < 8; hh++) a += scw[(row * 8 + hh) * 512 + tid];
            a *= 0.125f;
        }
        out[O6 + row * 512 + tid] = a;
    }
    const float* pr = pred + row * NVOC;
    float m = -3.0e38f;
    for (int v = tid; v < NVOC; v += 512) m = fmaxf(m, pr[v]);
#pragma unroll
    for (int o = 32; o; o >>= 1) m = fmaxf(m, __shfl_xor(m, o, 64));
    if ((tid & 63) == 0) red[tid >> 6] = m;
    __syncthreads();
#pragma unroll
    for (int i = 0; i < 8; i++) m = fmaxf(m, red[i]);
    __syncthreads();
    float s = 0.f;
    for (int v = tid; v < NVOC; v += 512) s += __expf(pr[v] - m);
#pragma unroll
    for (int o = 32; o; o >>= 1) s += __shfl_xor(s, o, 64);
    if ((tid & 63) == 0) red[tid >> 6] = s;
    __syncthreads();
    if (tid == 0) {
        float tot = 0.f;
#pragma unroll
        for (int i = 0; i < 8; i++) tot += red[i];
        rowmax[row] = m; rowsum[row] = tot;
        int b = row >> 4;
        float w = __expf(pr[x[b]] - m) / tot;
        wsq[row] = w;
        out[O9 + row] = w;
    }
}

// ===== vocab outputs + it/amw computation. grid (20, 8), 512 thr =====
__global__ __launch_bounds__(512)
void k_vocab(const float* __restrict__ pred, const float* __restrict__ rowmax,
             const float* __restrict__ rowsum, const float* __restrict__ wsq,
             const float* __restrict__ gumbel, int* __restrict__ it,
             float* __restrict__ out)
{
    int b = blockIdx.y;
    int tid = threadIdx.x;
    __shared__ int s_amw;
    if (tid == 0) {
        float bw = -3.0e38f; int bj = 0;
#pragma unroll
        for (int pp = 0; pp < 16; pp++) {
            float wv = wsq[b * 16 + pp];
            if (wv > bw) { bw = wv; bj = pp; }
        }
        s_amw = bj;
    }
    if (blockIdx.x == 0 && tid < 16) {
        float best = -3.0e38f; int bi = 0;
#pragma unroll
        for (int pp = 0; pp < 16; pp++) {
            float v = logf(wsq[b * 16 + pp] + 1e-10f) + gumbel[(b * 16 + tid) * 16 + pp];
            if (v > best) { best = v; bi = pp; }
        }
        it[b * 16 + tid] = bi;
    }
    __syncthreads();
    int v = blockIdx.x * 512 + tid;
    if (v >= NVOC) return;
    int amw = s_amw;
    float ga = 0.f, as = 0.f;
#pragma unroll
    for (int p = 0; p < 16; p++) {
        int rr = b * 16 + p;
        float pv = pred[rr * NVOC + v];
        ga += pv;
        as += __expf(pv - rowmax[rr]) * (1.f / rowsum[rr]);
    }
    out[O3 + b * NVOC + v] = ga * (1.f / 16.f);
    out[O2 + b * NVOC + v] = as * (1.f / 16.f);
    out[O4 + b * NVOC + v] = pred[(b * 16 + amw) * NVOC + v];
}

// ===== K / Vs resample + misc outputs. grid 4096 x 256 grid-stride =====
__global__ __launch_bounds__(256)
void k_resample(const float* __restrict__ Kin, const float* __restrict__ kws,
                const int* __restrict__ it, const int* __restrict__ t_ptr,
                const float* __restrict__ r, const float* __restrict__ epsz,
                const float* __restrict__ zws, const int* __restrict__ Iin,
                float* __restrict__ out)
{
    int t = *t_ptr;
    const f32x4* K4  = (const f32x4*)Kin;
    const f32x4* kw4 = (const f32x4*)kws;
    const f32x4* r4  = (const f32x4*)r;
    const f32x4* e4  = (const f32x4*)epsz;
    const f32x4* z4  = (const f32x4*)zws;
    f32x4* oK = (f32x4*)(out + O7);
    f32x4* oV = (f32x4*)(out + O8);
    const int total = 128 * 512 * 128;
    const int total2 = total + 16384;
    for (int i = blockIdx.x * 256 + threadIdx.x; i < total2; i += gridDim.x * 256) {
        if (i < total) {
            int lane = i & 127;
            int row = i >> 7;
            int s = row & 511;
            int bp = row >> 9;
            int b = bp >> 4;
            f32x4 vK, vV;
            if (s > t) {
                vK = __builtin_nontemporal_load(&K4[i]);
                vV = vK;
            } else {
                int ip = it[bp];
                int ip2 = it[b * 16 + ip];
                if (s == t) {
                    vK = kw4[(b * 16 + ip) * 128 + lane];
                    vV = kw4[(b * 16 + ip2) * 128 + lane];
                } else {
                    vK = K4[((b * 16 + ip) * 512 + s) * 128 + lane];
                    vV = K4[((b * 16 + ip2) * 512 + s) * 128 + lane];
                }
            }
            __builtin_nontemporal_store(vK, &oK[i]);
            __builtin_nontemporal_store(vV, &oV[i]);
        } else {
            int j = i - total;
            int fidx = j * 4;
            ((f32x4*)(out + O0))[j] = r4[j];
            ((f32x4*)(out + O5))[j] = e4[j];
            int row = fidx >> 9, d0 = fidx & 511;
            int b = row >> 4;
            int ip = it[row];
            ((f32x4*)(out + O1))[j] = z4[((b * 16 + ip) << 7) + (d0 >> 2)];
#pragma unroll
            for (int k = 0; k < 4; k++) {
                int s = d0 + k;
                float iv;
                if (s < t)       iv = (float)Iin[((b * 16 + ip) << 9) + s];
                else if (s == t) iv = (float)ip;
                else             iv = (float)Iin[row * 512 + s];
                out[O10 + fidx + k] = iv;
            }
        }
    }
}

extern "C" void kernel_launch(void* const* d_in, const int* in_sizes, int n_in,
                              void* d_out, int out_size, void* d_ws, size_t ws_size,
                              hipStream_t stream) {
    const float* r      = (const float*)d_in[0];
    const int*   x      = (const int*)d_in[1];
    const float* Kin    = (const float*)d_in[2];
    const float* Vin    = (const float*)d_in[3];
    const int*   Iin    = (const int*)d_in[5];
    const int*   t_ptr  = (const int*)d_in[6];
    const float* eps_q  = (const float*)d_in[7];
    const float* eps_k  = (const float*)d_in[8];
    const float* eps_v  = (const float*)d_in[9];
    const float* eps_z  = (const float*)d_in[10];
    const float* gumbel = (const float*)d_in[11];
    const float* Wq = (const float*)d_in[12]; const float* bq = (const float*)d_in[13];
    const float* Wk = (const float*)d_in[14]; const float* bk = (const float*)d_in[15];
    const float* Wv = (const float*)d_in[16]; const float* bv = (const float*)d_in[17];
    const float* Wo = (const float*)d_in[18]; const float* bo = (const float*)d_in[19];
    const float* ln1_g = (const float*)d_in[20]; const float* ln1_b = (const float*)d_in[21];
    const float* ln3_g = (const float*)d_in[22]; const float* ln3_b = (const float*)d_in[23];
    const float* W1 = (const float*)d_in[24]; const float* b1 = (const float*)d_in[25];
    const float* W2 = (const float*)d_in[26]; const float* b2 = (const float*)d_in[27];
    const float* Wout = (const float*)d_in[28]; const float* bout = (const float*)d_in[29];

    float* ws  = (float*)d_ws;
    float* q   = ws + WQ;
    float* kv  = ws + WK;
    float* vv  = ws + WV;
    float* zh  = ws + WZH;
    float* zp  = ws + WZ;
    float* o1  = ws + WO1;
    float* h1  = ws + WH1;
    float* pr  = ws + WPRED;
    float* rmx = ws + WMAX;
    float* rsm = ws + WSUM;
    float* wsq = ws + WWSQ;
    int*   itw = (int*)(ws + WIT);
    float* f2p = ws + WF2P;
    float* scw = ws + WSC;
    float* outp = (float*)d_out;

    k_qkv<<<dim3(8, 16, 3), 512, 0, stream>>>(r, Wq, bq, eps_q, q, Wk, bk, eps_k, kv, Wv, bv, eps_v, vv);
    k_attn<<<dim3(128, 8), 512, 0, stream>>>(q, kv, vv, Kin, Vin, t_ptr, zh, scw);
    k_zproj<<<dim3(8, 16), 512, 0, stream>>>(zh, Wo, bo, eps_z, zp);
    k_ffn1<<<dim3(32, 16), 512, 0, stream>>>(zp, r, ln1_g, ln1_b, W1, b1, o1, h1);
    k_ffn2p<<<dim3(8, 16, 4), 512, 0, stream>>>(h1, W2, f2p);
    k_pred<<<dim3(40, 8), 512, 0, stream>>>(f2p, b2, o1, ln3_g, ln3_b, Wout, bout, pr);
    k_soft<<<128, 512, 0, stream>>>(pr, x, scw, t_ptr, rmx, rsm, wsq, outp);
    k_vocab<<<dim3(20, 8), 512, 0, stream>>>(pr, rmx, rsm, wsq, gumbel, itw, outp);
    k_resample<<<4096, 256, 0, stream>>>(Kin, kv, itw, t_ptr, r, eps_z, zp, Iin, outp);
}